// Round 2
// baseline (236.429 us; speedup 1.0000x reference)
//
#include <hip/hip_runtime.h>

// Problem constants
#define Bn 2
#define Mn 25000
#define Nn 100000
#define MK 400000           // Mn*Kn points per batch
#define GN_EPS 1e-5f
#define NEG_BIG (-3.402823466e+38f)
#define LOG2E 1.44269504088896340736f
#define MASK_NEG (-60000.f)

#define G1 512              // gatherx blocks per batch
#define G2 512              // pass2 blocks per batch
#define G3 3125             // pass3 blocks per batch: 128 pts each, exact (3125*128 = 400000)

// ws layout (float offsets). No atomics; every region fully written before read.
#define BEFF_OFF 0        // [64]      at_w1@pe_b2 + at_b1
#define B1P_OFF  64       // [2][64]   folded gn1 bias
#define AB1P_OFF 192      // [2][64]   folded gn2 bias: a2*ab1 + c2
#define AB2L_OFF 320      // [64]      ab2 * log2e
#define WF16_OFF 384      // 3*4096 f16: w2, aw2*log2e, Weff    (6144 floats)
#define AW1P_OFF 6528     // [2][4096] f16 folded a2*aw1        (4096 floats)
#define W1F_OFF  10624    // [2][64][8] f16 a1-folded W1, K-pad (512 floats)
#define MSK_OFF  11136    // [2][25024] u16 packed mask         (25024 floats)
#define SP_OFF   36160    // [2][G1][16] gatherx moment partials(16384 floats)
#define YP_OFF   52544    // [2][G2][128] pass2 partials        (131072 floats)
#define YS_OFF   183616   // [2][128] doubles: reduced sums     (512 floats)
#define KXT_OFF  184128   // [2][Nn][4] f32 transposed kx       (800000 floats)
#define QT_OFF   984128   // [2][Mn][4] f32 transposed q        (200000 floats)
#define XF_OFF   1184128  // [2][MK][4] f16 cached local_pattern(1600000 floats)
// total: 2784128 floats ≈ 11.14 MB

typedef _Float16 hf8 __attribute__((ext_vector_type(8)));
typedef _Float16 hf4 __attribute__((ext_vector_type(4)));
typedef _Float16 hf2 __attribute__((ext_vector_type(2)));
typedef float f32x16 __attribute__((ext_vector_type(16)));

__device__ __forceinline__ f32x16 mfma16(hf8 a, hf8 b, f32x16 c) {
    return __builtin_amdgcn_mfma_f32_32x32x16_f16(a, b, c, 0, 0, 0);
}
__device__ __forceinline__ f32x16 splat16(float v) {
    f32x16 x;
#pragma unroll
    for (int r = 0; r < 16; ++r) x[r] = v;
    return x;
}
__device__ __forceinline__ hf8 zero8() {
    hf8 z;
#pragma unroll
    for (int j = 0; j < 8; ++j) z[j] = (_Float16)0.f;
    return z;
}
__device__ __forceinline__ hf2 pkcvt(float a, float b) {
    return __builtin_bit_cast(hf2, __builtin_amdgcn_cvt_pkrtz(a, b));
}
__device__ __forceinline__ hf2 pkrelu(hf2 v) {
    hf2 z; z[0] = (_Float16)0.f; z[1] = (_Float16)0.f;
    return __builtin_elementwise_max(v, z);
}
__device__ __forceinline__ float waveSum(float v) {
#pragma unroll
    for (int s = 32; s; s >>= 1) v += __shfl_down(v, s, 64);
    return v;
}
#define ROWFN(r, lane) (((r) & 3) + 8*((r) >> 2) + 4*((lane) >> 5))
// XOR swizzle: stride-64 LDS rows, bank-rotate by row. col in halves.
// Keeps hf2 (4B) and hf8 (16B) accesses aligned (only bits 3..5 toggled).
#define SWZH(row, col) ((col) ^ ((((row) & 7)) << 3))

// ---------------- Kernel 0: transpose kx/q to [n][4] ----------------
__global__ __launch_bounds__(256) void prep0_kernel(
    const float* __restrict__ q, const float* __restrict__ kx,
    float* __restrict__ ws)
{
    float4* kxt = (float4*)(ws + KXT_OFF);
    float4* qt  = (float4*)(ws + QT_OFF);
    for (int e = blockIdx.x*256 + threadIdx.x; e < 2*Nn; e += gridDim.x*256) {
        const int b = e / Nn, n = e % Nn;
        float4 v;
        v.x = kx[(b*3+0)*Nn + n]; v.y = kx[(b*3+1)*Nn + n];
        v.z = kx[(b*3+2)*Nn + n]; v.w = 0.f;
        kxt[e] = v;
    }
    for (int e = blockIdx.x*256 + threadIdx.x; e < 2*Mn; e += gridDim.x*256) {
        const int b = e / Mn, m = e % Mn;
        float4 v;
        v.x = q[(b*3+0)*Mn + m]; v.y = q[(b*3+1)*Mn + m];
        v.z = q[(b*3+2)*Mn + m]; v.w = 0.f;
        qt[e] = v;
    }
}

// ---------------- Kernel A: gather once -> x-cache (f16) + packed mask + moments ----------------
__global__ __launch_bounds__(256) void gatherx_kernel(
    const int* __restrict__ idx, const int* __restrict__ mask,
    float* __restrict__ ws)
{
    __shared__ float red[4][16];
    const int b = blockIdx.y;
    const float4* kxt = (const float4*)(ws + KXT_OFF) + (size_t)b*Nn;
    const float4* qt  = (const float4*)(ws + QT_OFF)  + (size_t)b*Mn;
    _Float16* xf = (_Float16*)(ws + XF_OFF);
    unsigned short* m16 = (unsigned short*)(ws + MSK_OFF) + (size_t)b*25024;
    float v[14];
#pragma unroll
    for (int j = 0; j < 14; ++j) v[j] = 0.f;

    for (int i = blockIdx.x*256 + threadIdx.x; i < MK; i += G1*256) {
        const int mm = i >> 4;
        const int id = idx[(size_t)b*MK + i];
        const float4 kv = kxt[id];
        const float4 qv = qt[mm];
        const float ox = kv.x - qv.x, oy = kv.y - qv.y, oz = kv.z - qv.z;
        const float d  = sqrtf(ox*ox + oy*oy + oz*oz);
        const float inv = 1.0f / fmaxf(d, 1e-12f);
        const float x0 = ox*inv, x1 = oy*inv, x2 = oz*inv, x3 = d;

        const hf2 lo = pkcvt(x0, x1);
        const hf2 hi = pkcvt(x2, x3);
        hf4 pk;
        pk[0] = lo[0]; pk[1] = lo[1]; pk[2] = hi[0]; pk[3] = hi[1];
        *(hf4*)&xf[((size_t)b*MK + i)*4] = pk;

        const unsigned long long mb = __ballot(mask[(size_t)b*MK + i] != 0);
        if ((threadIdx.x & 63) == 0)
            *(unsigned long long*)&m16[i >> 4] = mb;

        v[0] += x0; v[1] += x1; v[2] += x2; v[3] += x3;
        v[4] += x0*x0; v[5] += x0*x1; v[6] += x0*x2; v[7] += x0*x3;
        v[8] += x1*x1; v[9] += x1*x2; v[10] += x1*x3;
        v[11] += x2*x2; v[12] += x2*x3; v[13] += x3*x3;
    }
    const int lane = threadIdx.x & 63, wv = threadIdx.x >> 6;
#pragma unroll
    for (int j = 0; j < 14; ++j) v[j] = waveSum(v[j]);
    if (lane == 0) {
#pragma unroll
        for (int j = 0; j < 14; ++j) red[wv][j] = v[j];
    }
    __syncthreads();
    if (threadIdx.x < 14)
        ws[SP_OFF + ((size_t)b*G1 + blockIdx.x)*16 + threadIdx.x] =
            red[0][threadIdx.x] + red[1][threadIdx.x] + red[2][threadIdx.x] + red[3][threadIdx.x];
}

// ---------------- Kernel B: block0: moments -> gn1 fold + beff + ab2 prescale;
//                  blocks 1..16: Weff + f16 weight conversion (data-independent) ----------------
__global__ void prep1_kernel(
    const float* __restrict__ ws_r,
    const float* __restrict__ w1, const float* __restrict__ b1,
    const float* __restrict__ g1, const float* __restrict__ be1,
    const float* __restrict__ w2, const float* __restrict__ pe_b2,
    const float* __restrict__ aw1, const float* __restrict__ ab1,
    const float* __restrict__ aw2, const float* __restrict__ ab2,
    float* __restrict__ ws)
{
    const int t = threadIdx.x;
    _Float16* WF = (_Float16*)(ws + WF16_OFF);

    if (blockIdx.x > 0) {
        // one element per thread: 16 blocks x 256 threads = 4096 elements
        const int e = (blockIdx.x - 1)*256 + t;
        const int o = e >> 6, c = e & 63;
        WF[e]        = (_Float16)w2[e];
        WF[4096 + e] = (_Float16)(aw2[e] * LOG2E);
        float acc = 0.f;
        for (int d = 0; d < 64; ++d) acc = fmaf(aw1[o*64 + d], w2[d*64 + c], acc);
        WF[8192 + e] = (_Float16)acc;
        return;
    }

    __shared__ double S[2][14];
    __shared__ double Sp[28][8];
    __shared__ float Eh[2][64], Eq[2][64];

    // parallel reduce of the 2*14 moment sums over G1 partials:
    // 224 threads = 28 (b,j) pairs x 8 sub-slices, then 8-way LDS tree.
    if (t < 224) {
        const int p = t >> 3, sub = t & 7;
        const int b = p / 14, j = p % 14;
        const float* src = ws_r + SP_OFF + (size_t)b*G1*16 + j;
        double acc = 0.0;
        for (int g = sub; g < G1; g += 8)
            acc += (double)src[(size_t)g*16];
        Sp[p][sub] = acc;
    }
    __syncthreads();
    if (t < 28) {
        double acc = 0.0;
#pragma unroll
        for (int s = 0; s < 8; ++s) acc += Sp[t][s];
        S[t / 14][t % 14] = acc;
    }
    __syncthreads();

    if (t < 128) {
        const int b = t >> 6, o = t & 63;
        const double inv = 1.0 / (double)MK;
        double mu[4];
#pragma unroll
        for (int c = 0; c < 4; ++c) mu[c] = S[b][c] * inv;
        double m2[4][4];
        {
            const int map[4][4] = {{0,1,2,3},{1,4,5,6},{2,5,7,8},{3,6,8,9}};
#pragma unroll
            for (int c = 0; c < 4; ++c)
#pragma unroll
                for (int c2 = 0; c2 < 4; ++c2)
                    m2[c][c2] = S[b][4 + map[c][c2]] * inv;
        }
        double w[4];
#pragma unroll
        for (int c = 0; c < 4; ++c) w[c] = (double)w1[o*4 + c];
        double s = 0.0, qd = 0.0;
#pragma unroll
        for (int c = 0; c < 4; ++c) {
            s += w[c] * mu[c];
#pragma unroll
            for (int c2 = 0; c2 < 4; ++c2) qd += w[c]*w[c2]*m2[c][c2];
        }
        const double bb = (double)b1[o];
        Eh[b][o] = (float)(s + bb);
        Eq[b][o] = (float)(qd + 2.0*bb*s + bb*bb);
    }
    __syncthreads();
    if (t < 128) {
        const int b = t >> 6, o = t & 63, g = o & ~7;
        float mg = 0.f, qg = 0.f;
#pragma unroll
        for (int j = 0; j < 8; ++j) { mg += Eh[b][g + j]; qg += Eq[b][g + j]; }
        mg *= 0.125f; qg *= 0.125f;
        const float var = fmaxf(qg - mg*mg, 0.f);
        const float a = g1[o] / sqrtf(var + GN_EPS);
        const float c1v = be1[o] - mg*a;
        _Float16* W1F = (_Float16*)(ws + W1F_OFF);
        hf8 wrow;
#pragma unroll
        for (int c = 0; c < 4; ++c) wrow[c] = (_Float16)(a * w1[o*4 + c]);
#pragma unroll
        for (int c = 4; c < 8; ++c) wrow[c] = (_Float16)0.f;
        *(hf8*)&W1F[(b*64 + o)*8] = wrow;
        ws[B1P_OFF + b*64 + o] = fmaf(a, b1[o], c1v);
    }
    if (t < 64) {
        float acc = ab1[t];
        for (int d = 0; d < 64; ++d) acc = fmaf(aw1[t*64 + d], pe_b2[d], acc);
        ws[BEFF_OFF + t] = acc;
    } else if (t < 128) {
        ws[AB2L_OFF + (t - 64)] = ab2[t - 64] * LOG2E;
    }
}

// ---------------- Kernel C: Σy, Σy² (y = Weff@r1), all-MFMA, interleaved cols ----------------
__global__ __launch_bounds__(256, 4) void pass2_kernel(
    const float* __restrict__ cws, float* __restrict__ ws)
{
    __shared__ __align__(16) _Float16 Xs[4][32][72];
    const int b = blockIdx.y;
    const int tid = threadIdx.x, lane = tid & 63, wv = tid >> 6;
    const int colA = lane & 31;
    const int klo = (lane >> 5) * 8;
    const _Float16* xf  = (const _Float16*)(cws + XF_OFF);
    const _Float16* WFe = (const _Float16*)(cws + WF16_OFF) + 8192;  // Weff
    const _Float16* W1F = (const _Float16*)(cws + W1F_OFF);

    hf8 BW[2][4];
#pragma unroll
    for (int jc = 0; jc < 2; ++jc)
#pragma unroll
        for (int ks = 0; ks < 4; ++ks)
            BW[jc][ks] = *(const hf8*)&WFe[(2*colA + jc)*64 + 16*ks + klo];
    hf8 BX[2];
    if (klo == 0) {
        BX[0] = *(const hf8*)&W1F[(b*64 + 2*colA)*8];
        BX[1] = *(const hf8*)&W1F[(b*64 + 2*colA + 1)*8];
    } else { BX[0] = zero8(); BX[1] = zero8(); }
    const float bias0 = cws[B1P_OFF + b*64 + 2*colA];
    const float bias1 = cws[B1P_OFF + b*64 + 2*colA + 1];

    float sh[2] = {0.f, 0.f}, sq[2] = {0.f, 0.f};

    for (int base = blockIdx.x * 128; base < MK; base += G2 * 128) {
        const int pt0 = base + 32*wv;
        hf8 ax = zero8();
        if (klo == 0) {
            hf4 xv = *(const hf4*)&xf[((size_t)b*MK + pt0 + colA)*4];
#pragma unroll
            for (int j = 0; j < 4; ++j) ax[j] = xv[j];
        }
        f32x16 r0 = splat16(bias0), r1t = splat16(bias1);
        r0  = mfma16(ax, BX[0], r0);
        r1t = mfma16(ax, BX[1], r1t);
#pragma unroll
        for (int r = 0; r < 16; ++r) {
            const int row = ROWFN(r, lane);
            *(hf2*)&Xs[wv][row][2*colA] = pkrelu(pkcvt(r0[r], r1t[r]));
        }
        hf8 A[4];
#pragma unroll
        for (int ks = 0; ks < 4; ++ks)
            A[ks] = *(const hf8*)&Xs[wv][colA][16*ks + klo];
#pragma unroll
        for (int jc = 0; jc < 2; ++jc) {
            f32x16 C = splat16(0.f);
#pragma unroll
            for (int ks = 0; ks < 4; ++ks) C = mfma16(A[ks], BW[jc][ks], C);
#pragma unroll
            for (int r = 0; r < 16; ++r) {
                const float vy = C[r];
                sh[jc] += vy;
                sq[jc] = fmaf(vy, vy, sq[jc]);
            }
        }
    }

#pragma unroll
    for (int jc = 0; jc < 2; ++jc) {
        sh[jc] += __shfl_xor(sh[jc], 32, 64);
        sq[jc] += __shfl_xor(sq[jc], 32, 64);
    }
    __syncthreads();
    float* red = (float*)Xs;   // [4][128]
    if (lane < 32) {
#pragma unroll
        for (int jc = 0; jc < 2; ++jc) {
            red[wv*128 +      2*colA + jc] = sh[jc];
            red[wv*128 + 64 + 2*colA + jc] = sq[jc];
        }
    }
    __syncthreads();
    if (tid < 128) {
        const float v = red[tid] + red[128 + tid] + red[256 + tid] + red[384 + tid];
        ws[YP_OFF + ((size_t)b*G2 + blockIdx.x)*128 + tid] = v;
    }
}

// ---------------- Kernel D1: parallel reduce of pass2 partials (one block per output) ----------------
__global__ __launch_bounds__(64) void prep2a_kernel(
    const float* __restrict__ ws_r, float* __restrict__ ws)
{
    const int o2 = blockIdx.x;            // [0,256): b = o2>>7, i = o2&127
    const int b = o2 >> 7, i = o2 & 127;
    const float* p = ws_r + YP_OFF + (size_t)b*G2*128 + i;
    double acc = 0.0;
    for (int g = threadIdx.x; g < G2; g += 64) acc += (double)p[(size_t)g*128];
#pragma unroll
    for (int s = 32; s; s >>= 1) acc += __shfl_down(acc, s, 64);
    if (threadIdx.x == 0) ((double*)(ws + YS_OFF))[o2] = acc;
}

// ---------------- Kernel D2: gn2 coeffs + fold into aw1/ab1 ----------------
__global__ void prep2b_kernel(const float* __restrict__ ws_r,
                              const float* __restrict__ g2, const float* __restrict__ be2,
                              const float* __restrict__ aw1, const float* __restrict__ ab1,
                              float* __restrict__ ws)
{
    __shared__ float EH[2][64], EQ[2][64];
    __shared__ float A2s[2][64];
    const int t = threadIdx.x;   // 256
    const double* YS = (const double*)(ws_r + YS_OFF);
    if (t < 128) {
        const int b = t >> 6, o = t & 63;
        const double invMK = 1.0 / (double)MK;
        const double my = YS[b*128 + o] * invMK;
        const double qy = YS[b*128 + 64 + o] * invMK;
        const double beff = (double)ws_r[BEFF_OFF + o];
        EH[b][o] = (float)(my + beff);
        EQ[b][o] = (float)(qy + 2.0*beff*my + beff*beff);
    }
    __syncthreads();
    if (t < 128) {
        const int b = t >> 6, o = t & 63, g = o & ~7;
        float mg = 0.f, qg = 0.f;
#pragma unroll
        for (int j = 0; j < 8; ++j) { mg += EH[b][g + j]; qg += EQ[b][g + j]; }
        mg *= 0.125f; qg *= 0.125f;
        const float var = fmaxf(qg - mg*mg, 0.f);
        const float a = g2[o] / sqrtf(var + GN_EPS);
        A2s[b][o] = a;
        ws[AB1P_OFF + b*64 + o] = fmaf(a, ab1[o], be2[o] - mg*a);
    }
    __syncthreads();
    _Float16* AW1P = (_Float16*)(ws + AW1P_OFF);
    for (int e = t; e < 8192; e += 256) {
        const int b = e >> 12, oc = e & 4095, o = oc >> 6;
        AW1P[e] = (_Float16)(A2s[b][o] * aw1[oc]);
    }
}

// ---------------- Kernel E: one-tile-per-wave all-MFMA forward (32 pts/wave) ----------------
// Per-wave live state ~85-95 unified regs (2x f32x16 acc + 16 pe_pk + working)
// -> fits floor(512/5)=102 cap without spilling; LDS 16KB; 5 waves/SIMD target.
// 3125 blocks x 128 pts = exactly MK: no bounds checks anywhere.
__global__ __launch_bounds__(256, 5) void pass3_kernel(
    const float* __restrict__ b2,
    const float* __restrict__ cws, float* __restrict__ out)
{
    __shared__ __align__(16) _Float16 Xs[4][32][64];   // [wv][row][colSWZ] 16 KB
    float* O = (float*)Xs;                             // aliased after barrier: [64][9]

    const int b = blockIdx.y;
    const int tid = threadIdx.x;
    const int lane = tid & 63, wv = tid >> 6;
    const int colA = lane & 31;
    const int hi = lane >> 5;
    const int klo = hi * 8;
    const int pt0 = blockIdx.x * 128 + 32 * wv;

    const _Float16* xf   = (const _Float16*)(cws + XF_OFF);
    const _Float16* WF   = (const _Float16*)(cws + WF16_OFF);
    const _Float16* AW1P = (const _Float16*)(cws + AW1P_OFF) + (size_t)b*4096;
    const _Float16* W1F  = (const _Float16*)(cws + W1F_OFF);
    const unsigned short* m16 = (const unsigned short*)(cws + MSK_OFF) + (size_t)b*25024;

    const unsigned mbs = __builtin_amdgcn_readfirstlane(
        *(const unsigned*)(m16 + (pt0 >> 4)));

    // ---- r1 via MFMA from cached x ----
    {
        hf8 BX0, BX1, ax;
        if (klo == 0) {
            BX0 = *(const hf8*)&W1F[(b*64 + 2*colA)*8];
            BX1 = *(const hf8*)&W1F[(b*64 + 2*colA + 1)*8];
            ax = zero8();
            hf4 xv = *(const hf4*)&xf[((size_t)b*MK + pt0 + colA)*4];
#pragma unroll
            for (int j = 0; j < 4; ++j) ax[j] = xv[j];
        } else { BX0 = zero8(); BX1 = zero8(); ax = zero8(); }
        f32x16 r0  = splat16(cws[B1P_OFF + b*64 + 2*colA]);
        f32x16 r1t = splat16(cws[B1P_OFF + b*64 + 2*colA + 1]);
        r0  = mfma16(ax, BX0, r0);
        r1t = mfma16(ax, BX1, r1t);
#pragma unroll
        for (int r = 0; r < 16; ++r) {
            const int row = ROWFN(r, lane);
            *(hf2*)&Xs[wv][row][SWZH(row, 2*colA)] = pkrelu(pkcvt(r0[r], r1t[r]));
        }
    }

    // ---- GEMM1: pe = r1 @ w2^T + b2 ----
    hf2 pe_pk[16];   // packed pe kept for softmax (16 VGPRs)
    {
        f32x16 p00 = splat16(b2[2*colA]);
        f32x16 p01 = splat16(b2[2*colA + 1]);
#pragma unroll
        for (int ks = 0; ks < 4; ++ks) {
            const int off = SWZH(colA, 16*ks + klo);
            hf8 a0  = *(const hf8*)&Xs[wv][colA][off];
            hf8 b0f = *(const hf8*)&WF[(2*colA)*64 + 16*ks + klo];
            hf8 b1f = *(const hf8*)&WF[(2*colA + 1)*64 + 16*ks + klo];
            p00 = mfma16(a0, b0f, p00);
            p01 = mfma16(a0, b1f, p01);
        }
#pragma unroll
        for (int r = 0; r < 16; ++r) {
            const int row = ROWFN(r, lane);
            pe_pk[r] = pkcvt(p00[r], p01[r]);
            *(hf2*)&Xs[wv][row][SWZH(row, 2*colA)] = pe_pk[r];
        }
    }

    // ---- GEMM2: r2 = relu(pe @ (a2*aw1)^T + ab1') ----
    {
        f32x16 h00 = splat16(cws[AB1P_OFF + b*64 + 2*colA]);
        f32x16 h01 = splat16(cws[AB1P_OFF + b*64 + 2*colA + 1]);
#pragma unroll
        for (int ks = 0; ks < 4; ++ks) {
            const int off = SWZH(colA, 16*ks + klo);
            hf8 a0  = *(const hf8*)&Xs[wv][colA][off];
            hf8 b0f = *(const hf8*)&AW1P[(2*colA)*64 + 16*ks + klo];
            hf8 b1f = *(const hf8*)&AW1P[(2*colA + 1)*64 + 16*ks + klo];
            h00 = mfma16(a0, b0f, h00);
            h01 = mfma16(a0, b1f, h01);
        }
#pragma unroll
        for (int r = 0; r < 16; ++r) {
            const int row = ROWFN(r, lane);
            *(hf2*)&Xs[wv][row][SWZH(row, 2*colA)] = pkrelu(pkcvt(h00[r], h01[r]));
        }
    }

    // ---- GEMM3: logits(log2) = r2 @ (aw2*log2e)^T + ab2*log2e ----
    f32x16 l00 = splat16(cws[AB2L_OFF + 2*colA]);
    f32x16 l01 = splat16(cws[AB2L_OFF + 2*colA + 1]);
#pragma unroll
    for (int ks = 0; ks < 4; ++ks) {
        const int off = SWZH(colA, 16*ks + klo);
        hf8 a0  = *(const hf8*)&Xs[wv][colA][off];
        hf8 b0f = *(const hf8*)&WF[4096 + (2*colA)*64 + 16*ks + klo];
        hf8 b1f = *(const hf8*)&WF[4096 + (2*colA + 1)*64 + 16*ks + klo];
        l00 = mfma16(a0, b0f, l00);
        l01 = mfma16(a0, b1f, l01);
    }

    // ---- mask applied in registers (bit = row of C fragment; wave-uniform word) ----
    {
        const unsigned msh = mbs >> (4*hi);
#pragma unroll
        for (int r = 0; r < 16; ++r) {
            const int bit = (r & 3) + 8*(r >> 2);   // compile-time constant
            const bool k0 = (msh >> bit) & 1u;
            l00[r] = k0 ? l00[r] : MASK_NEG;
            l01[r] = k0 ? l01[r] : MASK_NEG;
        }
    }

    __syncthreads();   // all Xs reads done; O may alias Xs

    // ---- softmax over K=16 (exp2 domain) + weighted pe sum ----
    {
        auto softmax_tile = [&](const f32x16& lg, int j) {
#pragma unroll
            for (int mh = 0; mh < 2; ++mh) {
                float mx = lg[8*mh];
#pragma unroll
                for (int rr = 1; rr < 8; ++rr) mx = fmaxf(mx, lg[8*mh + rr]);
                mx = fmaxf(mx, __shfl_xor(mx, 32, 64));
                float se, sw = 0.f;
                if (((mbs >> (16*mh)) & 0xFFFFu) != 0u) {
                    se = 0.f;
#pragma unroll
                    for (int rr = 0; rr < 8; ++rr) {
                        const float e = exp2f(lg[8*mh + rr] - mx);
                        se += e;
                        sw = fmaf(e, (float)pe_pk[8*mh + rr][j], sw);
                    }
                } else {
                    se = 8.f;
#pragma unroll
                    for (int rr = 0; rr < 8; ++rr) sw += (float)pe_pk[8*mh + rr][j];
                }
                se += __shfl_xor(se, 32, 64);
                sw += __shfl_xor(sw, 32, 64);
                if (lane < 32)
                    O[(2*lane + j)*9 + (2*wv + mh)] = sw * __builtin_amdgcn_rcpf(se);
            }
        };
        softmax_tile(l00, 0);
        softmax_tile(l01, 1);
    }
    __syncthreads();

    {   // 64 ch x 8 m per block, one float2 per thread (all blocks full)
        const int o = tid >> 2, mq = (tid & 3) * 2;
        const int m0 = blockIdx.x * 8;
        float2 v;
        v.x = O[o*9 + mq]; v.y = O[o*9 + mq + 1];
        *(float2*)&out[((size_t)b*64 + o)*Mn + m0 + mq] = v;
    }
}

extern "C" void kernel_launch(void* const* d_in, const int* in_sizes, int n_in,
                              void* d_out, int out_size, void* d_ws, size_t ws_size,
                              hipStream_t stream) {
    (void)in_sizes; (void)n_in; (void)out_size; (void)ws_size;
    const float* q    = (const float*)d_in[0];
    const float* kx   = (const float*)d_in[1];
    const int*   idx  = (const int*)  d_in[2];
    const int*   mask = (const int*)  d_in[3];
    const float* w1   = (const float*)d_in[4];
    const float* b1   = (const float*)d_in[5];
    const float* g1   = (const float*)d_in[6];
    const float* be1  = (const float*)d_in[7];
    const float* w2   = (const float*)d_in[8];
    const float* b2   = (const float*)d_in[9];
    const float* aw1  = (const float*)d_in[10];
    const float* ab1  = (const float*)d_in[11];
    const float* g2   = (const float*)d_in[12];
    const float* be2  = (const float*)d_in[13];
    const float* aw2  = (const float*)d_in[14];
    const float* ab2  = (const float*)d_in[15];
    float* out = (float*)d_out;
    float* ws  = (float*)d_ws;

    prep0_kernel<<<256, 256, 0, stream>>>(q, kx, ws);
    gatherx_kernel<<<dim3(G1, Bn), 256, 0, stream>>>(idx, mask, ws);
    prep1_kernel<<<17, 256, 0, stream>>>(ws, w1, b1, g1, be1, w2, b2, aw1, ab1, aw2, ab2, ws);
    pass2_kernel<<<dim3(G2, Bn), 256, 0, stream>>>(ws, ws);
    prep2a_kernel<<<256, 64, 0, stream>>>(ws, ws);
    prep2b_kernel<<<1, 256, 0, stream>>>(ws, g2, be2, aw1, ab1, ws);
    pass3_kernel<<<dim3(G3, Bn), 256, 0, stream>>>(b2, ws, out);
}

// Round 3
// 201.324 us; speedup vs baseline: 1.1744x; 1.1744x over previous
//
#include <hip/hip_runtime.h>

// Problem constants
#define Bn 2
#define Mn 25000
#define Nn 100000
#define MK 400000           // Mn*Kn points per batch
#define GN_EPS 1e-5f
#define NEG_BIG (-3.402823466e+38f)
#define LOG2E 1.44269504088896340736f
#define MASK_NEG (-60000.f)

#define G1 512              // gatherx blocks per batch
#define G2 512              // pass2 blocks per batch

// ws layout (float offsets). No atomics; every region fully written before read.
#define BEFF_OFF 0        // [64]      at_w1@pe_b2 + at_b1
#define B1P_OFF  64       // [2][64]   folded gn1 bias
#define AB1P_OFF 192      // [2][64]   folded gn2 bias: a2*ab1 + c2
#define AB2L_OFF 320      // [64]      ab2 * log2e
#define WF16_OFF 384      // 3*4096 f16: w2, aw2*log2e, Weff    (6144 floats)
#define AW1P_OFF 6528     // [2][4096] f16 folded a2*aw1        (4096 floats)
#define W1F_OFF  10624    // [2][64][8] f16 a1-folded W1, K-pad (512 floats)
#define MSK_OFF  11136    // [2][25024] u16 packed mask         (25024 floats)
#define SP_OFF   36160    // [2][G1][16] gatherx moment partials(16384 floats)
#define YP_OFF   52544    // [2][G2][128] pass2 partials        (131072 floats)
#define YS_OFF   183616   // [2][128] doubles: reduced sums     (512 floats)
#define KXT_OFF  184128   // [2][Nn][4] f32 transposed kx       (800000 floats)
#define QT_OFF   984128   // [2][Mn][4] f32 transposed q        (200000 floats)
#define XF_OFF   1184128  // [2][MK][4] f16 cached local_pattern(1600000 floats)
// total: 2784128 floats ≈ 11.14 MB

typedef _Float16 hf8 __attribute__((ext_vector_type(8)));
typedef _Float16 hf4 __attribute__((ext_vector_type(4)));
typedef _Float16 hf2 __attribute__((ext_vector_type(2)));
typedef float f32x16 __attribute__((ext_vector_type(16)));

__device__ __forceinline__ f32x16 mfma16(hf8 a, hf8 b, f32x16 c) {
    return __builtin_amdgcn_mfma_f32_32x32x16_f16(a, b, c, 0, 0, 0);
}
__device__ __forceinline__ f32x16 splat16(float v) {
    f32x16 x;
#pragma unroll
    for (int r = 0; r < 16; ++r) x[r] = v;
    return x;
}
__device__ __forceinline__ hf8 zero8() {
    hf8 z;
#pragma unroll
    for (int j = 0; j < 8; ++j) z[j] = (_Float16)0.f;
    return z;
}
__device__ __forceinline__ hf2 pkcvt(float a, float b) {
    return __builtin_bit_cast(hf2, __builtin_amdgcn_cvt_pkrtz(a, b));
}
__device__ __forceinline__ hf2 pkrelu(hf2 v) {
    hf2 z; z[0] = (_Float16)0.f; z[1] = (_Float16)0.f;
    return __builtin_elementwise_max(v, z);
}
__device__ __forceinline__ float waveSum(float v) {
#pragma unroll
    for (int s = 32; s; s >>= 1) v += __shfl_down(v, s, 64);
    return v;
}
#define ROWFN(r, lane) (((r) & 3) + 8*((r) >> 2) + 4*((lane) >> 5))

// ---------------- Kernel 0: transpose kx/q to [n][4] ----------------
__global__ __launch_bounds__(256) void prep0_kernel(
    const float* __restrict__ q, const float* __restrict__ kx,
    float* __restrict__ ws)
{
    float4* kxt = (float4*)(ws + KXT_OFF);
    float4* qt  = (float4*)(ws + QT_OFF);
    for (int e = blockIdx.x*256 + threadIdx.x; e < 2*Nn; e += gridDim.x*256) {
        const int b = e / Nn, n = e % Nn;
        float4 v;
        v.x = kx[(b*3+0)*Nn + n]; v.y = kx[(b*3+1)*Nn + n];
        v.z = kx[(b*3+2)*Nn + n]; v.w = 0.f;
        kxt[e] = v;
    }
    for (int e = blockIdx.x*256 + threadIdx.x; e < 2*Mn; e += gridDim.x*256) {
        const int b = e / Mn, m = e % Mn;
        float4 v;
        v.x = q[(b*3+0)*Mn + m]; v.y = q[(b*3+1)*Mn + m];
        v.z = q[(b*3+2)*Mn + m]; v.w = 0.f;
        qt[e] = v;
    }
}

// ---------------- Kernel A: gather once -> x-cache (f16) + packed mask + moments ----------------
// Unroll-2 over grid-stride iterations: two idx->gather chains in flight per thread.
// Loop bounds are wave-uniform (G1*256 and MK are multiples of 64), so __ballot
// stays in uniform control flow.
__global__ __launch_bounds__(256) void gatherx_kernel(
    const int* __restrict__ idx, const int* __restrict__ mask,
    float* __restrict__ ws)
{
    __shared__ float red[4][16];
    const int b = blockIdx.y;
    const float4* kxt = (const float4*)(ws + KXT_OFF) + (size_t)b*Nn;
    const float4* qt  = (const float4*)(ws + QT_OFF)  + (size_t)b*Mn;
    _Float16* xf = (_Float16*)(ws + XF_OFF);
    unsigned short* m16 = (unsigned short*)(ws + MSK_OFF) + (size_t)b*25024;
    float v[14];
#pragma unroll
    for (int j = 0; j < 14; ++j) v[j] = 0.f;

    auto process = [&](int i, const float4 kv, const float4 qv, int mk) {
        const float ox = kv.x - qv.x, oy = kv.y - qv.y, oz = kv.z - qv.z;
        const float d  = sqrtf(ox*ox + oy*oy + oz*oz);
        const float inv = 1.0f / fmaxf(d, 1e-12f);
        const float x0 = ox*inv, x1 = oy*inv, x2 = oz*inv, x3 = d;

        const hf2 lo = pkcvt(x0, x1);
        const hf2 h2 = pkcvt(x2, x3);
        hf4 pk;
        pk[0] = lo[0]; pk[1] = lo[1]; pk[2] = h2[0]; pk[3] = h2[1];
        *(hf4*)&xf[((size_t)b*MK + i)*4] = pk;

        const unsigned long long mb = __ballot(mk != 0);
        if ((threadIdx.x & 63) == 0)
            *(unsigned long long*)&m16[i >> 4] = mb;

        v[0] += x0; v[1] += x1; v[2] += x2; v[3] += x3;
        v[4] += x0*x0; v[5] += x0*x1; v[6] += x0*x2; v[7] += x0*x3;
        v[8] += x1*x1; v[9] += x1*x2; v[10] += x1*x3;
        v[11] += x2*x2; v[12] += x2*x3; v[13] += x3*x3;
    };

    const int stride = G1*256;
    int i = blockIdx.x*256 + threadIdx.x;
    for (; i + stride < MK; i += 2*stride) {
        const int iB = i + stride;
        const int idA = idx[(size_t)b*MK + i];
        const int idB = idx[(size_t)b*MK + iB];
        const int mA  = mask[(size_t)b*MK + i];
        const int mB  = mask[(size_t)b*MK + iB];
        const float4 kvA = kxt[idA];
        const float4 kvB = kxt[idB];
        const float4 qvA = qt[i >> 4];
        const float4 qvB = qt[iB >> 4];
        process(i,  kvA, qvA, mA);
        process(iB, kvB, qvB, mB);
    }
    for (; i < MK; i += stride) {
        const int id = idx[(size_t)b*MK + i];
        const int mk = mask[(size_t)b*MK + i];
        const float4 kv = kxt[id];
        const float4 qv = qt[i >> 4];
        process(i, kv, qv, mk);
    }

    const int lane = threadIdx.x & 63, wv = threadIdx.x >> 6;
#pragma unroll
    for (int j = 0; j < 14; ++j) v[j] = waveSum(v[j]);
    if (lane == 0) {
#pragma unroll
        for (int j = 0; j < 14; ++j) red[wv][j] = v[j];
    }
    __syncthreads();
    if (threadIdx.x < 14)
        ws[SP_OFF + ((size_t)b*G1 + blockIdx.x)*16 + threadIdx.x] =
            red[0][threadIdx.x] + red[1][threadIdx.x] + red[2][threadIdx.x] + red[3][threadIdx.x];
}

// ---------------- Kernel B: block0: moments -> gn1 fold + beff + ab2 prescale;
//                  blocks 1..16: Weff + f16 weight conversion (data-independent) ----------------
__global__ void prep1_kernel(
    const float* __restrict__ ws_r,
    const float* __restrict__ w1, const float* __restrict__ b1,
    const float* __restrict__ g1, const float* __restrict__ be1,
    const float* __restrict__ w2, const float* __restrict__ pe_b2,
    const float* __restrict__ aw1, const float* __restrict__ ab1,
    const float* __restrict__ aw2, const float* __restrict__ ab2,
    float* __restrict__ ws)
{
    const int t = threadIdx.x;
    _Float16* WF = (_Float16*)(ws + WF16_OFF);

    if (blockIdx.x > 0) {
        // one element per thread: 16 blocks x 256 threads = 4096 elements
        const int e = (blockIdx.x - 1)*256 + t;
        const int o = e >> 6, c = e & 63;
        WF[e]        = (_Float16)w2[e];
        WF[4096 + e] = (_Float16)(aw2[e] * LOG2E);
        float acc = 0.f;
        for (int d = 0; d < 64; ++d) acc = fmaf(aw1[o*64 + d], w2[d*64 + c], acc);
        WF[8192 + e] = (_Float16)acc;
        return;
    }

    __shared__ double S[2][14];
    __shared__ double Sp[28][8];
    __shared__ float Eh[2][64], Eq[2][64];

    // parallel reduce of the 2*14 moment sums over G1 partials:
    // 224 threads = 28 (b,j) pairs x 8 sub-slices, then 8-way LDS tree.
    if (t < 224) {
        const int p = t >> 3, sub = t & 7;
        const int b = p / 14, j = p % 14;
        const float* src = ws_r + SP_OFF + (size_t)b*G1*16 + j;
        double acc = 0.0;
        for (int g = sub; g < G1; g += 8)
            acc += (double)src[(size_t)g*16];
        Sp[p][sub] = acc;
    }
    __syncthreads();
    if (t < 28) {
        double acc = 0.0;
#pragma unroll
        for (int s = 0; s < 8; ++s) acc += Sp[t][s];
        S[t / 14][t % 14] = acc;
    }
    __syncthreads();

    if (t < 128) {
        const int b = t >> 6, o = t & 63;
        const double inv = 1.0 / (double)MK;
        double mu[4];
#pragma unroll
        for (int c = 0; c < 4; ++c) mu[c] = S[b][c] * inv;
        double m2[4][4];
        {
            const int map[4][4] = {{0,1,2,3},{1,4,5,6},{2,5,7,8},{3,6,8,9}};
#pragma unroll
            for (int c = 0; c < 4; ++c)
#pragma unroll
                for (int c2 = 0; c2 < 4; ++c2)
                    m2[c][c2] = S[b][4 + map[c][c2]] * inv;
        }
        double w[4];
#pragma unroll
        for (int c = 0; c < 4; ++c) w[c] = (double)w1[o*4 + c];
        double s = 0.0, qd = 0.0;
#pragma unroll
        for (int c = 0; c < 4; ++c) {
            s += w[c] * mu[c];
#pragma unroll
            for (int c2 = 0; c2 < 4; ++c2) qd += w[c]*w[c2]*m2[c][c2];
        }
        const double bb = (double)b1[o];
        Eh[b][o] = (float)(s + bb);
        Eq[b][o] = (float)(qd + 2.0*bb*s + bb*bb);
    }
    __syncthreads();
    if (t < 128) {
        const int b = t >> 6, o = t & 63, g = o & ~7;
        float mg = 0.f, qg = 0.f;
#pragma unroll
        for (int j = 0; j < 8; ++j) { mg += Eh[b][g + j]; qg += Eq[b][g + j]; }
        mg *= 0.125f; qg *= 0.125f;
        const float var = fmaxf(qg - mg*mg, 0.f);
        const float a = g1[o] / sqrtf(var + GN_EPS);
        const float c1v = be1[o] - mg*a;
        _Float16* W1F = (_Float16*)(ws + W1F_OFF);
        hf8 wrow;
#pragma unroll
        for (int c = 0; c < 4; ++c) wrow[c] = (_Float16)(a * w1[o*4 + c]);
#pragma unroll
        for (int c = 4; c < 8; ++c) wrow[c] = (_Float16)0.f;
        *(hf8*)&W1F[(b*64 + o)*8] = wrow;
        ws[B1P_OFF + b*64 + o] = fmaf(a, b1[o], c1v);
    }
    if (t < 64) {
        float acc = ab1[t];
        for (int d = 0; d < 64; ++d) acc = fmaf(aw1[t*64 + d], pe_b2[d], acc);
        ws[BEFF_OFF + t] = acc;
    } else if (t < 128) {
        ws[AB2L_OFF + (t - 64)] = ab2[t - 64] * LOG2E;
    }
}

// ---------------- Kernel C: Σy, Σy² (y = Weff@r1), all-MFMA, interleaved cols ----------------
__global__ __launch_bounds__(256, 4) void pass2_kernel(
    const float* __restrict__ cws, float* __restrict__ ws)
{
    __shared__ __align__(16) _Float16 Xs[4][32][72];
    const int b = blockIdx.y;
    const int tid = threadIdx.x, lane = tid & 63, wv = tid >> 6;
    const int colA = lane & 31;
    const int klo = (lane >> 5) * 8;
    const _Float16* xf  = (const _Float16*)(cws + XF_OFF);
    const _Float16* WFe = (const _Float16*)(cws + WF16_OFF) + 8192;  // Weff
    const _Float16* W1F = (const _Float16*)(cws + W1F_OFF);

    hf8 BW[2][4];
#pragma unroll
    for (int jc = 0; jc < 2; ++jc)
#pragma unroll
        for (int ks = 0; ks < 4; ++ks)
            BW[jc][ks] = *(const hf8*)&WFe[(2*colA + jc)*64 + 16*ks + klo];
    hf8 BX[2];
    if (klo == 0) {
        BX[0] = *(const hf8*)&W1F[(b*64 + 2*colA)*8];
        BX[1] = *(const hf8*)&W1F[(b*64 + 2*colA + 1)*8];
    } else { BX[0] = zero8(); BX[1] = zero8(); }
    const float bias0 = cws[B1P_OFF + b*64 + 2*colA];
    const float bias1 = cws[B1P_OFF + b*64 + 2*colA + 1];

    float sh[2] = {0.f, 0.f}, sq[2] = {0.f, 0.f};

    for (int base = blockIdx.x * 128; base < MK; base += G2 * 128) {
        const int pt0 = base + 32*wv;
        hf8 ax = zero8();
        if (klo == 0) {
            hf4 xv = *(const hf4*)&xf[((size_t)b*MK + pt0 + colA)*4];
#pragma unroll
            for (int j = 0; j < 4; ++j) ax[j] = xv[j];
        }
        f32x16 r0 = splat16(bias0), r1t = splat16(bias1);
        r0  = mfma16(ax, BX[0], r0);
        r1t = mfma16(ax, BX[1], r1t);
#pragma unroll
        for (int r = 0; r < 16; ++r) {
            const int row = ROWFN(r, lane);
            *(hf2*)&Xs[wv][row][2*colA] = pkrelu(pkcvt(r0[r], r1t[r]));
        }
        hf8 A[4];
#pragma unroll
        for (int ks = 0; ks < 4; ++ks)
            A[ks] = *(const hf8*)&Xs[wv][colA][16*ks + klo];
#pragma unroll
        for (int jc = 0; jc < 2; ++jc) {
            f32x16 C = splat16(0.f);
#pragma unroll
            for (int ks = 0; ks < 4; ++ks) C = mfma16(A[ks], BW[jc][ks], C);
#pragma unroll
            for (int r = 0; r < 16; ++r) {
                const float vy = C[r];
                sh[jc] += vy;
                sq[jc] = fmaf(vy, vy, sq[jc]);
            }
        }
    }

#pragma unroll
    for (int jc = 0; jc < 2; ++jc) {
        sh[jc] += __shfl_xor(sh[jc], 32, 64);
        sq[jc] += __shfl_xor(sq[jc], 32, 64);
    }
    __syncthreads();
    float* red = (float*)Xs;   // [4][128]
    if (lane < 32) {
#pragma unroll
        for (int jc = 0; jc < 2; ++jc) {
            red[wv*128 +      2*colA + jc] = sh[jc];
            red[wv*128 + 64 + 2*colA + jc] = sq[jc];
        }
    }
    __syncthreads();
    if (tid < 128) {
        const float v = red[tid] + red[128 + tid] + red[256 + tid] + red[384 + tid];
        ws[YP_OFF + ((size_t)b*G2 + blockIdx.x)*128 + tid] = v;
    }
}

// ---------------- Kernel D1: parallel reduce of pass2 partials (one block per output) ----------------
__global__ __launch_bounds__(64) void prep2a_kernel(
    const float* __restrict__ ws_r, float* __restrict__ ws)
{
    const int o2 = blockIdx.x;            // [0,256): b = o2>>7, i = o2&127
    const int b = o2 >> 7, i = o2 & 127;
    const float* p = ws_r + YP_OFF + (size_t)b*G2*128 + i;
    double acc = 0.0;
    for (int g = threadIdx.x; g < G2; g += 64) acc += (double)p[(size_t)g*128];
#pragma unroll
    for (int s = 32; s; s >>= 1) acc += __shfl_down(acc, s, 64);
    if (threadIdx.x == 0) ((double*)(ws + YS_OFF))[o2] = acc;
}

// ---------------- Kernel D2: gn2 coeffs + fold into aw1/ab1 ----------------
__global__ void prep2b_kernel(const float* __restrict__ ws_r,
                              const float* __restrict__ g2, const float* __restrict__ be2,
                              const float* __restrict__ aw1, const float* __restrict__ ab1,
                              float* __restrict__ ws)
{
    __shared__ float EH[2][64], EQ[2][64];
    __shared__ float A2s[2][64];
    const int t = threadIdx.x;   // 256
    const double* YS = (const double*)(ws_r + YS_OFF);
    if (t < 128) {
        const int b = t >> 6, o = t & 63;
        const double invMK = 1.0 / (double)MK;
        const double my = YS[b*128 + o] * invMK;
        const double qy = YS[b*128 + 64 + o] * invMK;
        const double beff = (double)ws_r[BEFF_OFF + o];
        EH[b][o] = (float)(my + beff);
        EQ[b][o] = (float)(qy + 2.0*beff*my + beff*beff);
    }
    __syncthreads();
    if (t < 128) {
        const int b = t >> 6, o = t & 63, g = o & ~7;
        float mg = 0.f, qg = 0.f;
#pragma unroll
        for (int j = 0; j < 8; ++j) { mg += EH[b][g + j]; qg += EQ[b][g + j]; }
        mg *= 0.125f; qg *= 0.125f;
        const float var = fmaxf(qg - mg*mg, 0.f);
        const float a = g2[o] / sqrtf(var + GN_EPS);
        A2s[b][o] = a;
        ws[AB1P_OFF + b*64 + o] = fmaf(a, ab1[o], be2[o] - mg*a);
    }
    __syncthreads();
    _Float16* AW1P = (_Float16*)(ws + AW1P_OFF);
    for (int e = t; e < 8192; e += 256) {
        const int b = e >> 12, oc = e & 4095, o = oc >> 6;
        AW1P[e] = (_Float16)(A2s[b][o] * aw1[oc]);
    }
}

// ---------------- Kernel E: two-tile all-MFMA forward (64 pts/wave, B-fragments reused) ----------------
// Round-0 proven structure (stride-72 LDS, 4 MFMA chains/wave) + mask applied in
// registers (deletes 4 rank-1 mask MFMAs + pad LDS writes/reads, layout unchanged).
__global__ __launch_bounds__(256, 3) void pass3_kernel(
    const float* __restrict__ b2,
    const float* __restrict__ cws, float* __restrict__ out)
{
    __shared__ __align__(16) _Float16 Xs[8][32][72];   // [2*wv+t][row][col] 36.9 KB
    float* O = (float*)Xs;                             // aliased after barrier: [64][17]

    const int b = blockIdx.y;
    const int base = blockIdx.x * 256;                 // grid.x = 1563; last block partial
    const int tid = threadIdx.x;
    const int lane = tid & 63, wv = tid >> 6;
    const int colA = lane & 31;
    const int hi = lane >> 5;
    const int klo = hi * 8;

    const _Float16* xf   = (const _Float16*)(cws + XF_OFF);
    const _Float16* WF   = (const _Float16*)(cws + WF16_OFF);
    const _Float16* AW1P = (const _Float16*)(cws + AW1P_OFF) + (size_t)b*4096;
    const _Float16* W1F  = (const _Float16*)(cws + W1F_OFF);
    const unsigned short* m16 = (const unsigned short*)(cws + MSK_OFF) + (size_t)b*25024;

    int pt0[2];
    pt0[0] = base + 64*wv;
    pt0[1] = base + 64*wv + 32;
    unsigned mb[2];
#pragma unroll
    for (int t = 0; t < 2; ++t)
        mb[t] = (pt0[t] < MK) ? *(const unsigned*)(m16 + (pt0[t] >> 4)) : 0u;
    const unsigned mbs0 = __builtin_amdgcn_readfirstlane(mb[0]);
    const unsigned mbs1 = __builtin_amdgcn_readfirstlane(mb[1]);

    // ---- r1 via MFMA from cached x (both tiles; BX shared) ----
    {
        hf8 BX0, BX1;
        if (klo == 0) {
            BX0 = *(const hf8*)&W1F[(b*64 + 2*colA)*8];
            BX1 = *(const hf8*)&W1F[(b*64 + 2*colA + 1)*8];
        } else { BX0 = zero8(); BX1 = zero8(); }
        const float bias0 = cws[B1P_OFF + b*64 + 2*colA];
        const float bias1 = cws[B1P_OFF + b*64 + 2*colA + 1];
#pragma unroll
        for (int t = 0; t < 2; ++t) {
            hf8 ax = zero8();
            if (klo == 0 && pt0[t] < MK) {
                hf4 xv = *(const hf4*)&xf[((size_t)b*MK + pt0[t] + colA)*4];
#pragma unroll
                for (int j = 0; j < 4; ++j) ax[j] = xv[j];
            }
            f32x16 r0 = splat16(bias0), r1t = splat16(bias1);
            r0  = mfma16(ax, BX0, r0);
            r1t = mfma16(ax, BX1, r1t);
#pragma unroll
            for (int r = 0; r < 16; ++r) {
                const int row = ROWFN(r, lane);
                *(hf2*)&Xs[2*wv + t][row][2*colA] = pkrelu(pkcvt(r0[r], r1t[r]));
            }
        }
    }

    // ---- GEMM1: pe = r1 @ w2^T + b2 (B reused across tiles) ----
    hf2 pe_pk[2][16];   // packed pe kept for softmax (32 VGPRs)
    {
        f32x16 p00 = splat16(b2[2*colA]);
        f32x16 p01 = splat16(b2[2*colA + 1]);
        f32x16 p10 = p00, p11 = p01;
#pragma unroll
        for (int ks = 0; ks < 4; ++ks) {
            const int off = 16*ks + klo;
            hf8 a0  = *(const hf8*)&Xs[2*wv    ][colA][off];
            hf8 a1  = *(const hf8*)&Xs[2*wv + 1][colA][off];
            hf8 b0f = *(const hf8*)&WF[(2*colA)*64 + off];
            hf8 b1f = *(const hf8*)&WF[(2*colA + 1)*64 + off];
            p00 = mfma16(a0, b0f, p00);
            p01 = mfma16(a0, b1f, p01);
            p10 = mfma16(a1, b0f, p10);
            p11 = mfma16(a1, b1f, p11);
        }
#pragma unroll
        for (int r = 0; r < 16; ++r) {
            const int row = ROWFN(r, lane);
            pe_pk[0][r] = pkcvt(p00[r], p01[r]);
            pe_pk[1][r] = pkcvt(p10[r], p11[r]);
            *(hf2*)&Xs[2*wv    ][row][2*colA] = pe_pk[0][r];
            *(hf2*)&Xs[2*wv + 1][row][2*colA] = pe_pk[1][r];
        }
    }

    // ---- GEMM2: r2 = relu(pe @ (a2*aw1)^T + ab1') ----
    {
        f32x16 h00 = splat16(cws[AB1P_OFF + b*64 + 2*colA]);
        f32x16 h01 = splat16(cws[AB1P_OFF + b*64 + 2*colA + 1]);
        f32x16 h10 = h00, h11 = h01;
#pragma unroll
        for (int ks = 0; ks < 4; ++ks) {
            const int off = 16*ks + klo;
            hf8 a0  = *(const hf8*)&Xs[2*wv    ][colA][off];
            hf8 a1  = *(const hf8*)&Xs[2*wv + 1][colA][off];
            hf8 b0f = *(const hf8*)&AW1P[(2*colA)*64 + off];
            hf8 b1f = *(const hf8*)&AW1P[(2*colA + 1)*64 + off];
            h00 = mfma16(a0, b0f, h00);
            h01 = mfma16(a0, b1f, h01);
            h10 = mfma16(a1, b0f, h10);
            h11 = mfma16(a1, b1f, h11);
        }
#pragma unroll
        for (int r = 0; r < 16; ++r) {
            const int row = ROWFN(r, lane);
            *(hf2*)&Xs[2*wv    ][row][2*colA] = pkrelu(pkcvt(h00[r], h01[r]));
            *(hf2*)&Xs[2*wv + 1][row][2*colA] = pkrelu(pkcvt(h10[r], h11[r]));
        }
    }

    // ---- GEMM3: logits(log2) = r2 @ (aw2*log2e)^T + ab2*log2e ----
    f32x16 l00 = splat16(cws[AB2L_OFF + 2*colA]);
    f32x16 l01 = splat16(cws[AB2L_OFF + 2*colA + 1]);
    f32x16 l10 = l00, l11 = l01;
#pragma unroll
    for (int ks = 0; ks < 4; ++ks) {
        const int off = 16*ks + klo;
        hf8 a0  = *(const hf8*)&Xs[2*wv    ][colA][off];
        hf8 a1  = *(const hf8*)&Xs[2*wv + 1][colA][off];
        hf8 b0f = *(const hf8*)&WF[4096 + (2*colA)*64 + off];
        hf8 b1f = *(const hf8*)&WF[4096 + (2*colA + 1)*64 + off];
        l00 = mfma16(a0, b0f, l00);
        l01 = mfma16(a0, b1f, l01);
        l10 = mfma16(a1, b0f, l10);
        l11 = mfma16(a1, b1f, l11);
    }

    // ---- mask applied in registers (bit = point row of C fragment; wave-uniform words) ----
    {
        const unsigned msh0 = mbs0 >> (4*hi);
        const unsigned msh1 = mbs1 >> (4*hi);
#pragma unroll
        for (int r = 0; r < 16; ++r) {
            const int bit = (r & 3) + 8*(r >> 2);   // compile-time constant
            const bool k0 = (msh0 >> bit) & 1u;
            const bool k1 = (msh1 >> bit) & 1u;
            l00[r] = k0 ? l00[r] : MASK_NEG;
            l01[r] = k0 ? l01[r] : MASK_NEG;
            l10[r] = k1 ? l10[r] : MASK_NEG;
            l11[r] = k1 ? l11[r] : MASK_NEG;
        }
    }

    __syncthreads();   // all Xs reads done; O may alias Xs

    // ---- softmax over K=16 (exp2 domain) + weighted pe sum ----
    {
        auto softmax_tile = [&](const f32x16& lg, const hf2* pp, unsigned mbst,
                                int t, int j) {
#pragma unroll
            for (int mh = 0; mh < 2; ++mh) {
                float mx = lg[8*mh];
#pragma unroll
                for (int rr = 1; rr < 8; ++rr) mx = fmaxf(mx, lg[8*mh + rr]);
                mx = fmaxf(mx, __shfl_xor(mx, 32, 64));
                float se, sw = 0.f;
                if (((mbst >> (16*mh)) & 0xFFFFu) != 0u) {
                    se = 0.f;
#pragma unroll
                    for (int rr = 0; rr < 8; ++rr) {
                        const float e = exp2f(lg[8*mh + rr] - mx);
                        se += e;
                        sw = fmaf(e, (float)pp[8*mh + rr][j], sw);
                    }
                } else {
                    se = 8.f;
#pragma unroll
                    for (int rr = 0; rr < 8; ++rr) sw += (float)pp[8*mh + rr][j];
                }
                se += __shfl_xor(se, 32, 64);
                sw += __shfl_xor(sw, 32, 64);
                if (lane < 32)
                    O[(2*lane + j)*17 + (4*wv + 2*t + mh)] = sw * __builtin_amdgcn_rcpf(se);
            }
        };
        softmax_tile(l00, pe_pk[0], mbs0, 0, 0);
        softmax_tile(l01, pe_pk[0], mbs0, 0, 1);
        softmax_tile(l10, pe_pk[1], mbs1, 1, 0);
        softmax_tile(l11, pe_pk[1], mbs1, 1, 1);
    }
    __syncthreads();

    {   // 64 ch x 16 m per block, one float4 per thread
        const int o = tid >> 2, mq = (tid & 3) * 4;
        const int m0 = blockIdx.x * 16;
        if (m0 + mq < Mn) {
            float4 v;
            v.x = O[o*17 + mq];     v.y = O[o*17 + mq + 1];
            v.z = O[o*17 + mq + 2]; v.w = O[o*17 + mq + 3];
            *(float4*)&out[((size_t)b*64 + o)*Mn + m0 + mq] = v;
        }
    }
}

extern "C" void kernel_launch(void* const* d_in, const int* in_sizes, int n_in,
                              void* d_out, int out_size, void* d_ws, size_t ws_size,
                              hipStream_t stream) {
    (void)in_sizes; (void)n_in; (void)out_size; (void)ws_size;
    const float* q    = (const float*)d_in[0];
    const float* kx   = (const float*)d_in[1];
    const int*   idx  = (const int*)  d_in[2];
    const int*   mask = (const int*)  d_in[3];
    const float* w1   = (const float*)d_in[4];
    const float* b1   = (const float*)d_in[5];
    const float* g1   = (const float*)d_in[6];
    const float* be1  = (const float*)d_in[7];
    const float* w2   = (const float*)d_in[8];
    const float* b2   = (const float*)d_in[9];
    const float* aw1  = (const float*)d_in[10];
    const float* ab1  = (const float*)d_in[11];
    const float* g2   = (const float*)d_in[12];
    const float* be2  = (const float*)d_in[13];
    const float* aw2  = (const float*)d_in[14];
    const float* ab2  = (const float*)d_in[15];
    float* out = (float*)d_out;
    float* ws  = (float*)d_ws;

    prep0_kernel<<<256, 256, 0, stream>>>(q, kx, ws);
    gatherx_kernel<<<dim3(G1, Bn), 256, 0, stream>>>(idx, mask, ws);
    prep1_kernel<<<17, 256, 0, stream>>>(ws, w1, b1, g1, be1, w2, b2, aw1, ab1, aw2, ab2, ws);
    pass2_kernel<<<dim3(G2, Bn), 256, 0, stream>>>(ws, ws);
    prep2a_kernel<<<256, 64, 0, stream>>>(ws, ws);
    prep2b_kernel<<<1, 256, 0, stream>>>(ws, g2, be2, aw1, ab1, ws);
    pass3_kernel<<<dim3((MK + 255)/256, Bn), 256, 0, stream>>>(b2, ws, out);
}

// Round 5
// 194.528 us; speedup vs baseline: 1.2154x; 1.0349x over previous
//
#include <hip/hip_runtime.h>

// Problem constants
#define Bn 2
#define Mn 25000
#define Nn 100000
#define MK 400000           // Mn*Kn points per batch
#define GN_EPS 1e-5f
#define NEG_BIG (-3.402823466e+38f)
#define LOG2E 1.44269504088896340736f
#define MASK_NEG (-60000.f)

#define G1 512              // gatherx blocks per batch
#define G2 512              // pass2 blocks per batch

// ws layout (float offsets). No atomics; every region fully written before read.
#define BEFF_OFF 0        // [64]      at_w1@pe_b2 + at_b1
#define B1P_OFF  64       // [2][64]   folded gn1 bias
#define AB1P_OFF 192      // [2][64]   folded gn2 bias: a2*ab1 + c2
#define AB2L_OFF 320      // [64]      ab2 * log2e
#define WF16_OFF 384      // 3*4096 f16: w2, aw2*log2e, Weff    (6144 floats)
#define AW1P_OFF 6528     // [2][4096] f16 folded a2*aw1        (4096 floats)
#define W1F_OFF  10624    // [2][64][8] f16 a1-folded W1, K-pad (512 floats)
#define MSK_OFF  11136    // [2][25024] u16 packed mask         (25024 floats)
#define SP_OFF   36160    // [2][G1][16] gatherx moment partials(16384 floats)
#define YP_OFF   52544    // [2][G2][128] pass2 partials        (131072 floats)
#define YS_OFF   183616   // [2][128] doubles: reduced sums     (512 floats)
#define KXT_OFF  184128   // [2][Nn][4] f32 transposed kx       (800000 floats)
#define QT_OFF   984128   // [2][Mn][4] f32 transposed q        (200000 floats)
#define XF_OFF   1184128  // [2][MK][4] f16 cached local_pattern(1600000 floats)
// total: 2784128 floats ≈ 11.14 MB

typedef _Float16 hf8 __attribute__((ext_vector_type(8)));
typedef _Float16 hf4 __attribute__((ext_vector_type(4)));
typedef _Float16 hf2 __attribute__((ext_vector_type(2)));
typedef float f32x16 __attribute__((ext_vector_type(16)));

__device__ __forceinline__ f32x16 mfma16(hf8 a, hf8 b, f32x16 c) {
    return __builtin_amdgcn_mfma_f32_32x32x16_f16(a, b, c, 0, 0, 0);
}
__device__ __forceinline__ f32x16 splat16(float v) {
    f32x16 x;
#pragma unroll
    for (int r = 0; r < 16; ++r) x[r] = v;
    return x;
}
__device__ __forceinline__ hf8 zero8() {
    hf8 z;
#pragma unroll
    for (int j = 0; j < 8; ++j) z[j] = (_Float16)0.f;
    return z;
}
__device__ __forceinline__ hf2 pkcvt(float a, float b) {
    return __builtin_bit_cast(hf2, __builtin_amdgcn_cvt_pkrtz(a, b));
}
__device__ __forceinline__ hf2 pkrelu(hf2 v) {
    hf2 z; z[0] = (_Float16)0.f; z[1] = (_Float16)0.f;
    return __builtin_elementwise_max(v, z);
}
__device__ __forceinline__ float waveSum(float v) {
#pragma unroll
    for (int s = 32; s; s >>= 1) v += __shfl_down(v, s, 64);
    return v;
}
#define ROWFN(r, lane) (((r) & 3) + 8*((r) >> 2) + 4*((lane) >> 5))

// ---------------- Kernel 0: transpose kx/q to [n][4] ----------------
__global__ __launch_bounds__(256) void prep0_kernel(
    const float* __restrict__ q, const float* __restrict__ kx,
    float* __restrict__ ws)
{
    float4* kxt = (float4*)(ws + KXT_OFF);
    float4* qt  = (float4*)(ws + QT_OFF);
    for (int e = blockIdx.x*256 + threadIdx.x; e < 2*Nn; e += gridDim.x*256) {
        const int b = e / Nn, n = e % Nn;
        float4 v;
        v.x = kx[(b*3+0)*Nn + n]; v.y = kx[(b*3+1)*Nn + n];
        v.z = kx[(b*3+2)*Nn + n]; v.w = 0.f;
        kxt[e] = v;
    }
    for (int e = blockIdx.x*256 + threadIdx.x; e < 2*Mn; e += gridDim.x*256) {
        const int b = e / Mn, m = e % Mn;
        float4 v;
        v.x = q[(b*3+0)*Mn + m]; v.y = q[(b*3+1)*Mn + m];
        v.z = q[(b*3+2)*Mn + m]; v.w = 0.f;
        qt[e] = v;
    }
}

// ---------------- Kernel A: gather once -> x-cache (f16) + packed mask + moments ----------------
__global__ __launch_bounds__(256) void gatherx_kernel(
    const int* __restrict__ idx, const int* __restrict__ mask,
    float* __restrict__ ws)
{
    __shared__ float red[4][16];
    const int b = blockIdx.y;
    const float4* kxt = (const float4*)(ws + KXT_OFF) + (size_t)b*Nn;
    const float4* qt  = (const float4*)(ws + QT_OFF)  + (size_t)b*Mn;
    _Float16* xf = (_Float16*)(ws + XF_OFF);
    unsigned short* m16 = (unsigned short*)(ws + MSK_OFF) + (size_t)b*25024;
    float v[14];
#pragma unroll
    for (int j = 0; j < 14; ++j) v[j] = 0.f;

    for (int i = blockIdx.x*256 + threadIdx.x; i < MK; i += G1*256) {
        const int mm = i >> 4;
        const int id = idx[(size_t)b*MK + i];
        const float4 kv = kxt[id];
        const float4 qv = qt[mm];
        const float ox = kv.x - qv.x, oy = kv.y - qv.y, oz = kv.z - qv.z;
        const float d  = sqrtf(ox*ox + oy*oy + oz*oz);
        const float inv = 1.0f / fmaxf(d, 1e-12f);
        const float x0 = ox*inv, x1 = oy*inv, x2 = oz*inv, x3 = d;

        const hf2 lo = pkcvt(x0, x1);
        const hf2 hi = pkcvt(x2, x3);
        hf4 pk;
        pk[0] = lo[0]; pk[1] = lo[1]; pk[2] = hi[0]; pk[3] = hi[1];
        *(hf4*)&xf[((size_t)b*MK + i)*4] = pk;

        const unsigned long long mb = __ballot(mask[(size_t)b*MK + i] != 0);
        if ((threadIdx.x & 63) == 0)
            *(unsigned long long*)&m16[i >> 4] = mb;

        v[0] += x0; v[1] += x1; v[2] += x2; v[3] += x3;
        v[4] += x0*x0; v[5] += x0*x1; v[6] += x0*x2; v[7] += x0*x3;
        v[8] += x1*x1; v[9] += x1*x2; v[10] += x1*x3;
        v[11] += x2*x2; v[12] += x2*x3; v[13] += x3*x3;
    }
    const int lane = threadIdx.x & 63, wv = threadIdx.x >> 6;
#pragma unroll
    for (int j = 0; j < 14; ++j) v[j] = waveSum(v[j]);
    if (lane == 0) {
#pragma unroll
        for (int j = 0; j < 14; ++j) red[wv][j] = v[j];
    }
    __syncthreads();
    if (threadIdx.x < 14)
        ws[SP_OFF + ((size_t)b*G1 + blockIdx.x)*16 + threadIdx.x] =
            red[0][threadIdx.x] + red[1][threadIdx.x] + red[2][threadIdx.x] + red[3][threadIdx.x];
}

// ---------------- Kernel B: block0: moments -> gn1 fold + beff + ab2 prescale;
//                  blocks 1..16: Weff + f16 weight conversion (data-independent) ----------------
__global__ void prep1_kernel(
    const float* __restrict__ ws_r,
    const float* __restrict__ w1, const float* __restrict__ b1,
    const float* __restrict__ g1, const float* __restrict__ be1,
    const float* __restrict__ w2, const float* __restrict__ pe_b2,
    const float* __restrict__ aw1, const float* __restrict__ ab1,
    const float* __restrict__ aw2, const float* __restrict__ ab2,
    float* __restrict__ ws)
{
    const int t = threadIdx.x;
    _Float16* WF = (_Float16*)(ws + WF16_OFF);

    if (blockIdx.x > 0) {
        // one element per thread: 16 blocks x 256 threads = 4096 elements
        const int e = (blockIdx.x - 1)*256 + t;
        const int o = e >> 6, c = e & 63;
        WF[e]        = (_Float16)w2[e];
        WF[4096 + e] = (_Float16)(aw2[e] * LOG2E);
        float acc = 0.f;
        for (int d = 0; d < 64; ++d) acc = fmaf(aw1[o*64 + d], w2[d*64 + c], acc);
        WF[8192 + e] = (_Float16)acc;
        return;
    }

    __shared__ double S[2][14];
    __shared__ float Eh[2][64], Eq[2][64];

    if (t < 28) {
        const int b = t / 14, j = t % 14;
        const float* p = ws_r + SP_OFF + (size_t)b*G1*16 + j;
        double acc = 0.0;
        for (int g = 0; g < G1; g += 4)
            acc += (double)p[(g+0)*16] + (double)p[(g+1)*16]
                 + (double)p[(g+2)*16] + (double)p[(g+3)*16];
        S[b][j] = acc;
    }
    __syncthreads();

    if (t < 128) {
        const int b = t >> 6, o = t & 63;
        const double inv = 1.0 / (double)MK;
        double mu[4];
#pragma unroll
        for (int c = 0; c < 4; ++c) mu[c] = S[b][c] * inv;
        double m2[4][4];
        {
            const int map[4][4] = {{0,1,2,3},{1,4,5,6},{2,5,7,8},{3,6,8,9}};
#pragma unroll
            for (int c = 0; c < 4; ++c)
#pragma unroll
                for (int c2 = 0; c2 < 4; ++c2)
                    m2[c][c2] = S[b][4 + map[c][c2]] * inv;
        }
        double w[4];
#pragma unroll
        for (int c = 0; c < 4; ++c) w[c] = (double)w1[o*4 + c];
        double s = 0.0, qd = 0.0;
#pragma unroll
        for (int c = 0; c < 4; ++c) {
            s += w[c] * mu[c];
#pragma unroll
            for (int c2 = 0; c2 < 4; ++c2) qd += w[c]*w[c2]*m2[c][c2];
        }
        const double bb = (double)b1[o];
        Eh[b][o] = (float)(s + bb);
        Eq[b][o] = (float)(qd + 2.0*bb*s + bb*bb);
    }
    __syncthreads();
    if (t < 128) {
        const int b = t >> 6, o = t & 63, g = o & ~7;
        float mg = 0.f, qg = 0.f;
#pragma unroll
        for (int j = 0; j < 8; ++j) { mg += Eh[b][g + j]; qg += Eq[b][g + j]; }
        mg *= 0.125f; qg *= 0.125f;
        const float var = fmaxf(qg - mg*mg, 0.f);
        const float a = g1[o] / sqrtf(var + GN_EPS);
        const float c1v = be1[o] - mg*a;
        _Float16* W1F = (_Float16*)(ws + W1F_OFF);
        hf8 wrow;
#pragma unroll
        for (int c = 0; c < 4; ++c) wrow[c] = (_Float16)(a * w1[o*4 + c]);
#pragma unroll
        for (int c = 4; c < 8; ++c) wrow[c] = (_Float16)0.f;
        *(hf8*)&W1F[(b*64 + o)*8] = wrow;
        ws[B1P_OFF + b*64 + o] = fmaf(a, b1[o], c1v);
    }
    if (t < 64) {
        float acc = ab1[t];
        for (int d = 0; d < 64; ++d) acc = fmaf(aw1[t*64 + d], pe_b2[d], acc);
        ws[BEFF_OFF + t] = acc;
    } else if (t < 128) {
        ws[AB2L_OFF + (t - 64)] = ab2[t - 64] * LOG2E;
    }
}

// ---------------- Kernel C: Σy, Σy² (y = Weff@r1), all-MFMA, interleaved cols ----------------
__global__ __launch_bounds__(256, 4) void pass2_kernel(
    const float* __restrict__ cws, float* __restrict__ ws)
{
    __shared__ __align__(16) _Float16 Xs[4][32][72];
    const int b = blockIdx.y;
    const int tid = threadIdx.x, lane = tid & 63, wv = tid >> 6;
    const int colA = lane & 31;
    const int klo = (lane >> 5) * 8;
    const _Float16* xf  = (const _Float16*)(cws + XF_OFF);
    const _Float16* WFe = (const _Float16*)(cws + WF16_OFF) + 8192;  // Weff
    const _Float16* W1F = (const _Float16*)(cws + W1F_OFF);

    hf8 BW[2][4];
#pragma unroll
    for (int jc = 0; jc < 2; ++jc)
#pragma unroll
        for (int ks = 0; ks < 4; ++ks)
            BW[jc][ks] = *(const hf8*)&WFe[(2*colA + jc)*64 + 16*ks + klo];
    hf8 BX[2];
    if (klo == 0) {
        BX[0] = *(const hf8*)&W1F[(b*64 + 2*colA)*8];
        BX[1] = *(const hf8*)&W1F[(b*64 + 2*colA + 1)*8];
    } else { BX[0] = zero8(); BX[1] = zero8(); }
    const float bias0 = cws[B1P_OFF + b*64 + 2*colA];
    const float bias1 = cws[B1P_OFF + b*64 + 2*colA + 1];

    float sh[2] = {0.f, 0.f}, sq[2] = {0.f, 0.f};

    for (int base = blockIdx.x * 128; base < MK; base += G2 * 128) {
        const int pt0 = base + 32*wv;
        hf8 ax = zero8();
        if (klo == 0) {
            hf4 xv = *(const hf4*)&xf[((size_t)b*MK + pt0 + colA)*4];
#pragma unroll
            for (int j = 0; j < 4; ++j) ax[j] = xv[j];
        }
        f32x16 r0 = splat16(bias0), r1t = splat16(bias1);
        r0  = mfma16(ax, BX[0], r0);
        r1t = mfma16(ax, BX[1], r1t);
#pragma unroll
        for (int r = 0; r < 16; ++r) {
            const int row = ROWFN(r, lane);
            *(hf2*)&Xs[wv][row][2*colA] = pkrelu(pkcvt(r0[r], r1t[r]));
        }
        hf8 A[4];
#pragma unroll
        for (int ks = 0; ks < 4; ++ks)
            A[ks] = *(const hf8*)&Xs[wv][colA][16*ks + klo];
#pragma unroll
        for (int jc = 0; jc < 2; ++jc) {
            f32x16 C = splat16(0.f);
#pragma unroll
            for (int ks = 0; ks < 4; ++ks) C = mfma16(A[ks], BW[jc][ks], C);
#pragma unroll
            for (int r = 0; r < 16; ++r) {
                const float vy = C[r];
                sh[jc] += vy;
                sq[jc] = fmaf(vy, vy, sq[jc]);
            }
        }
    }

#pragma unroll
    for (int jc = 0; jc < 2; ++jc) {
        sh[jc] += __shfl_xor(sh[jc], 32, 64);
        sq[jc] += __shfl_xor(sq[jc], 32, 64);
    }
    __syncthreads();
    float* red = (float*)Xs;   // [4][128]
    if (lane < 32) {
#pragma unroll
        for (int jc = 0; jc < 2; ++jc) {
            red[wv*128 +      2*colA + jc] = sh[jc];
            red[wv*128 + 64 + 2*colA + jc] = sq[jc];
        }
    }
    __syncthreads();
    if (tid < 128) {
        const float v = red[tid] + red[128 + tid] + red[256 + tid] + red[384 + tid];
        ws[YP_OFF + ((size_t)b*G2 + blockIdx.x)*128 + tid] = v;
    }
}

// ---------------- Kernel D1: parallel reduce of pass2 partials (one block per output) ----------------
__global__ __launch_bounds__(64) void prep2a_kernel(
    const float* __restrict__ ws_r, float* __restrict__ ws)
{
    const int o2 = blockIdx.x;            // [0,256): b = o2>>7, i = o2&127
    const int b = o2 >> 7, i = o2 & 127;
    const float* p = ws_r + YP_OFF + (size_t)b*G2*128 + i;
    double acc = 0.0;
    for (int g = threadIdx.x; g < G2; g += 64) acc += (double)p[(size_t)g*128];
#pragma unroll
    for (int s = 32; s; s >>= 1) acc += __shfl_down(acc, s, 64);
    if (threadIdx.x == 0) ((double*)(ws + YS_OFF))[o2] = acc;
}

// ---------------- Kernel D2: gn2 coeffs + fold into aw1/ab1 ----------------
__global__ void prep2b_kernel(const float* __restrict__ ws_r,
                              const float* __restrict__ g2, const float* __restrict__ be2,
                              const float* __restrict__ aw1, const float* __restrict__ ab1,
                              float* __restrict__ ws)
{
    __shared__ float EH[2][64], EQ[2][64];
    __shared__ float A2s[2][64];
    const int t = threadIdx.x;   // 256
    const double* YS = (const double*)(ws_r + YS_OFF);
    if (t < 128) {
        const int b = t >> 6, o = t & 63;
        const double invMK = 1.0 / (double)MK;
        const double my = YS[b*128 + o] * invMK;
        const double qy = YS[b*128 + 64 + o] * invMK;
        const double beff = (double)ws_r[BEFF_OFF + o];
        EH[b][o] = (float)(my + beff);
        EQ[b][o] = (float)(qy + 2.0*beff*my + beff*beff);
    }
    __syncthreads();
    if (t < 128) {
        const int b = t >> 6, o = t & 63, g = o & ~7;
        float mg = 0.f, qg = 0.f;
#pragma unroll
        for (int j = 0; j < 8; ++j) { mg += EH[b][g + j]; qg += EQ[b][g + j]; }
        mg *= 0.125f; qg *= 0.125f;
        const float var = fmaxf(qg - mg*mg, 0.f);
        const float a = g2[o] / sqrtf(var + GN_EPS);
        A2s[b][o] = a;
        ws[AB1P_OFF + b*64 + o] = fmaf(a, ab1[o], be2[o] - mg*a);
    }
    __syncthreads();
    _Float16* AW1P = (_Float16*)(ws + AW1P_OFF);
    for (int e = t; e < 8192; e += 256) {
        const int b = e >> 12, oc = e & 4095, o = oc >> 6;
        AW1P[e] = (_Float16)(A2s[b][o] * aw1[oc]);
    }
}

// ---------------- Kernel E: two-tile all-MFMA forward (64 pts/wave, B-fragments reused) ----------------
// Proven structure (stride-72 LDS, 4 MFMA chains/wave) + in-register mask.
// __launch_bounds__(256,4): unified reg need is 64 VGPR + 64 AGPR = 128 = floor(512/4);
// LDS 36.9KB x 4 blocks = 147KB < 160KB -> target 4 waves/SIMD (was ~3).
__global__ __launch_bounds__(256, 4) void pass3_kernel(
    const float* __restrict__ b2,
    const float* __restrict__ cws, float* __restrict__ out)
{
    __shared__ __align__(16) _Float16 Xs[8][32][72];   // [2*wv+t][row][col] 36.9 KB
    float* O = (float*)Xs;                             // aliased after barrier: [64][17]

    const int b = blockIdx.y;
    const int base = blockIdx.x * 256;                 // grid.x = 1563; last block partial
    const int tid = threadIdx.x;
    const int lane = tid & 63, wv = tid >> 6;
    const int colA = lane & 31;
    const int hi = lane >> 5;
    const int klo = hi * 8;

    const _Float16* xf   = (const _Float16*)(cws + XF_OFF);
    const _Float16* WF   = (const _Float16*)(cws + WF16_OFF);
    const _Float16* AW1P = (const _Float16*)(cws + AW1P_OFF) + (size_t)b*4096;
    const _Float16* W1F  = (const _Float16*)(cws + W1F_OFF);
    const unsigned short* m16 = (const unsigned short*)(cws + MSK_OFF) + (size_t)b*25024;

    int pt0[2];
    pt0[0] = base + 64*wv;
    pt0[1] = base + 64*wv + 32;
    unsigned mb[2];
#pragma unroll
    for (int t = 0; t < 2; ++t)
        mb[t] = (pt0[t] < MK) ? *(const unsigned*)(m16 + (pt0[t] >> 4)) : 0u;
    const unsigned mbs0 = __builtin_amdgcn_readfirstlane(mb[0]);
    const unsigned mbs1 = __builtin_amdgcn_readfirstlane(mb[1]);

    // ---- r1 via MFMA from cached x (both tiles; BX shared) ----
    {
        hf8 BX0, BX1;
        if (klo == 0) {
            BX0 = *(const hf8*)&W1F[(b*64 + 2*colA)*8];
            BX1 = *(const hf8*)&W1F[(b*64 + 2*colA + 1)*8];
        } else { BX0 = zero8(); BX1 = zero8(); }
        const float bias0 = cws[B1P_OFF + b*64 + 2*colA];
        const float bias1 = cws[B1P_OFF + b*64 + 2*colA + 1];
#pragma unroll
        for (int t = 0; t < 2; ++t) {
            hf8 ax = zero8();
            if (klo == 0 && pt0[t] < MK) {
                hf4 xv = *(const hf4*)&xf[((size_t)b*MK + pt0[t] + colA)*4];
#pragma unroll
                for (int j = 0; j < 4; ++j) ax[j] = xv[j];
            }
            f32x16 r0 = splat16(bias0), r1t = splat16(bias1);
            r0  = mfma16(ax, BX0, r0);
            r1t = mfma16(ax, BX1, r1t);
#pragma unroll
            for (int r = 0; r < 16; ++r) {
                const int row = ROWFN(r, lane);
                *(hf2*)&Xs[2*wv + t][row][2*colA] = pkrelu(pkcvt(r0[r], r1t[r]));
            }
        }
    }

    // ---- GEMM1: pe = r1 @ w2^T + b2 (B reused across tiles) ----
    hf2 pe_pk[2][16];   // packed pe kept for softmax (32 VGPRs)
    {
        f32x16 p00 = splat16(b2[2*colA]);
        f32x16 p01 = splat16(b2[2*colA + 1]);
        f32x16 p10 = p00, p11 = p01;
#pragma unroll
        for (int ks = 0; ks < 4; ++ks) {
            const int off = 16*ks + klo;
            hf8 a0  = *(const hf8*)&Xs[2*wv    ][colA][off];
            hf8 a1  = *(const hf8*)&Xs[2*wv + 1][colA][off];
            hf8 b0f = *(const hf8*)&WF[(2*colA)*64 + off];
            hf8 b1f = *(const hf8*)&WF[(2*colA + 1)*64 + off];
            p00 = mfma16(a0, b0f, p00);
            p01 = mfma16(a0, b1f, p01);
            p10 = mfma16(a1, b0f, p10);
            p11 = mfma16(a1, b1f, p11);
        }
#pragma unroll
        for (int r = 0; r < 16; ++r) {
            const int row = ROWFN(r, lane);
            pe_pk[0][r] = pkcvt(p00[r], p01[r]);
            pe_pk[1][r] = pkcvt(p10[r], p11[r]);
            *(hf2*)&Xs[2*wv    ][row][2*colA] = pe_pk[0][r];
            *(hf2*)&Xs[2*wv + 1][row][2*colA] = pe_pk[1][r];
        }
    }

    // ---- GEMM2: r2 = relu(pe @ (a2*aw1)^T + ab1') ----
    {
        f32x16 h00 = splat16(cws[AB1P_OFF + b*64 + 2*colA]);
        f32x16 h01 = splat16(cws[AB1P_OFF + b*64 + 2*colA + 1]);
        f32x16 h10 = h00, h11 = h01;
#pragma unroll
        for (int ks = 0; ks < 4; ++ks) {
            const int off = 16*ks + klo;
            hf8 a0  = *(const hf8*)&Xs[2*wv    ][colA][off];
            hf8 a1  = *(const hf8*)&Xs[2*wv + 1][colA][off];
            hf8 b0f = *(const hf8*)&AW1P[(2*colA)*64 + off];
            hf8 b1f = *(const hf8*)&AW1P[(2*colA + 1)*64 + off];
            h00 = mfma16(a0, b0f, h00);
            h01 = mfma16(a0, b1f, h01);
            h10 = mfma16(a1, b0f, h10);
            h11 = mfma16(a1, b1f, h11);
        }
#pragma unroll
        for (int r = 0; r < 16; ++r) {
            const int row = ROWFN(r, lane);
            *(hf2*)&Xs[2*wv    ][row][2*colA] = pkrelu(pkcvt(h00[r], h01[r]));
            *(hf2*)&Xs[2*wv + 1][row][2*colA] = pkrelu(pkcvt(h10[r], h11[r]));
        }
    }

    // ---- GEMM3: logits(log2) = r2 @ (aw2*log2e)^T + ab2*log2e ----
    f32x16 l00 = splat16(cws[AB2L_OFF + 2*colA]);
    f32x16 l01 = splat16(cws[AB2L_OFF + 2*colA + 1]);
    f32x16 l10 = l00, l11 = l01;
#pragma unroll
    for (int ks = 0; ks < 4; ++ks) {
        const int off = 16*ks + klo;
        hf8 a0  = *(const hf8*)&Xs[2*wv    ][colA][off];
        hf8 a1  = *(const hf8*)&Xs[2*wv + 1][colA][off];
        hf8 b0f = *(const hf8*)&WF[4096 + (2*colA)*64 + off];
        hf8 b1f = *(const hf8*)&WF[4096 + (2*colA + 1)*64 + off];
        l00 = mfma16(a0, b0f, l00);
        l01 = mfma16(a0, b1f, l01);
        l10 = mfma16(a1, b0f, l10);
        l11 = mfma16(a1, b1f, l11);
    }

    // ---- mask applied in registers (bit = point row of C fragment; wave-uniform words) ----
    {
        const unsigned msh0 = mbs0 >> (4*hi);
        const unsigned msh1 = mbs1 >> (4*hi);
#pragma unroll
        for (int r = 0; r < 16; ++r) {
            const int bit = (r & 3) + 8*(r >> 2);   // compile-time constant
            const bool k0 = (msh0 >> bit) & 1u;
            const bool k1 = (msh1 >> bit) & 1u;
            l00[r] = k0 ? l00[r] : MASK_NEG;
            l01[r] = k0 ? l01[r] : MASK_NEG;
            l10[r] = k1 ? l10[r] : MASK_NEG;
            l11[r] = k1 ? l11[r] : MASK_NEG;
        }
    }

    __syncthreads();   // all Xs reads done; O may alias Xs

    // ---- softmax over K=16 (exp2 domain) + weighted pe sum ----
    {
        auto softmax_tile = [&](const f32x16& lg, const hf2* pp, unsigned mbst,
                                int t, int j) {
#pragma unroll
            for (int mh = 0; mh < 2; ++mh) {
                float mx = lg[8*mh];
#pragma unroll
                for (int rr = 1; rr < 8; ++rr) mx = fmaxf(mx, lg[8*mh + rr]);
                mx = fmaxf(mx, __shfl_xor(mx, 32, 64));
                float se, sw = 0.f;
                if (((mbst >> (16*mh)) & 0xFFFFu) != 0u) {
                    se = 0.f;
#pragma unroll
                    for (int rr = 0; rr < 8; ++rr) {
                        const float e = exp2f(lg[8*mh + rr] - mx);
                        se += e;
                        sw = fmaf(e, (float)pp[8*mh + rr][j], sw);
                    }
                } else {
                    se = 8.f;
#pragma unroll
                    for (int rr = 0; rr < 8; ++rr) sw += (float)pp[8*mh + rr][j];
                }
                se += __shfl_xor(se, 32, 64);
                sw += __shfl_xor(sw, 32, 64);
                if (lane < 32)
                    O[(2*lane + j)*17 + (4*wv + 2*t + mh)] = sw * __builtin_amdgcn_rcpf(se);
            }
        };
        softmax_tile(l00, pe_pk[0], mbs0, 0, 0);
        softmax_tile(l01, pe_pk[0], mbs0, 0, 1);
        softmax_tile(l10, pe_pk[1], mbs1, 1, 0);
        softmax_tile(l11, pe_pk[1], mbs1, 1, 1);
    }
    __syncthreads();

    {   // 64 ch x 16 m per block, one float4 per thread
        const int o = tid >> 2, mq = (tid & 3) * 4;
        const int m0 = blockIdx.x * 16;
        if (m0 + mq < Mn) {
            float4 v;
            v.x = O[o*17 + mq];     v.y = O[o*17 + mq + 1];
            v.z = O[o*17 + mq + 2]; v.w = O[o*17 + mq + 3];
            *(float4*)&out[((size_t)b*64 + o)*Mn + m0 + mq] = v;
        }
    }
}

extern "C" void kernel_launch(void* const* d_in, const int* in_sizes, int n_in,
                              void* d_out, int out_size, void* d_ws, size_t ws_size,
                              hipStream_t stream) {
    (void)in_sizes; (void)n_in; (void)out_size; (void)ws_size;
    const float* q    = (const float*)d_in[0];
    const float* kx   = (const float*)d_in[1];
    const int*   idx  = (const int*)  d_in[2];
    const int*   mask = (const int*)  d_in[3];
    const float* w1   = (const float*)d_in[4];
    const float* b1   = (const float*)d_in[5];
    const float* g1   = (const float*)d_in[6];
    const float* be1  = (const float*)d_in[7];
    const float* w2   = (const float*)d_in[8];
    const float* b2   = (const float*)d_in[9];
    const float* aw1  = (const float*)d_in[10];
    const float* ab1  = (const float*)d_in[11];
    const float* g2   = (const float*)d_in[12];
    const float* be2  = (const float*)d_in[13];
    const float* aw2  = (const float*)d_in[14];
    const float* ab2  = (const float*)d_in[15];
    float* out = (float*)d_out;
    float* ws  = (float*)d_ws;

    prep0_kernel<<<256, 256, 0, stream>>>(q, kx, ws);
    gatherx_kernel<<<dim3(G1, Bn), 256, 0, stream>>>(idx, mask, ws);
    prep1_kernel<<<17, 256, 0, stream>>>(ws, w1, b1, g1, be1, w2, b2, aw1, ab1, aw2, ab2, ws);
    pass2_kernel<<<dim3(G2, Bn), 256, 0, stream>>>(ws, ws);
    prep2a_kernel<<<256, 64, 0, stream>>>(ws, ws);
    prep2b_kernel<<<1, 256, 0, stream>>>(ws, g2, be2, aw1, ab1, ws);
    pass3_kernel<<<dim3((MK + 255)/256, Bn), 256, 0, stream>>>(b2, ws, out);
}

// Round 6
// 193.650 us; speedup vs baseline: 1.2209x; 1.0045x over previous
//
#include <hip/hip_runtime.h>

// Problem constants
#define Bn 2
#define Mn 25000
#define Nn 100000
#define MK 400000           // Mn*Kn points per batch
#define GN_EPS 1e-5f
#define NEG_BIG (-3.402823466e+38f)
#define LOG2E 1.44269504088896340736f
#define MASK_NEG (-60000.f)

#define G1 512              // gatherx blocks per batch
#define G2 512              // pass2 blocks per batch

// ws layout (float offsets). No atomics; every region fully written before read.
#define BEFF_OFF 0        // [64]      at_w1@pe_b2 + at_b1
#define B1P_OFF  64       // [2][64]   folded gn1 bias
#define AB1P_OFF 192      // [2][64]   folded gn2 bias: a2*ab1 + c2
#define AB2L_OFF 320      // [64]      ab2 * log2e (written, no longer read: bias cancels in softmax)
#define WF16_OFF 384      // 3*4096 f16: w2, aw2*log2e, Weff    (6144 floats)
#define AW1P_OFF 6528     // [2][4096] f16 folded a2*aw1        (4096 floats)
#define W1F_OFF  10624    // [2][64][8] f16 a1-folded W1, K-pad (512 floats)
#define MSK_OFF  11136    // [2][25024] u16 packed mask         (25024 floats)
#define SP_OFF   36160    // [2][G1][16] gatherx moment partials(16384 floats)
#define YP_OFF   52544    // [2][G2][128] pass2 partials        (131072 floats)
#define YS_OFF   183616   // [2][128] doubles: reduced sums     (512 floats)
#define KXT_OFF  184128   // [2][Nn][4] f32 transposed kx       (800000 floats)
#define QT_OFF   984128   // [2][Mn][4] f32 transposed q        (200000 floats)
#define XF_OFF   1184128  // [2][MK][4] f16 cached local_pattern(1600000 floats)
// total: 2784128 floats ≈ 11.14 MB

typedef _Float16 hf8 __attribute__((ext_vector_type(8)));
typedef _Float16 hf4 __attribute__((ext_vector_type(4)));
typedef _Float16 hf2 __attribute__((ext_vector_type(2)));
typedef float f32x16 __attribute__((ext_vector_type(16)));

__device__ __forceinline__ f32x16 mfma16(hf8 a, hf8 b, f32x16 c) {
    return __builtin_amdgcn_mfma_f32_32x32x16_f16(a, b, c, 0, 0, 0);
}
__device__ __forceinline__ f32x16 splat16(float v) {
    f32x16 x;
#pragma unroll
    for (int r = 0; r < 16; ++r) x[r] = v;
    return x;
}
__device__ __forceinline__ hf8 zero8() {
    hf8 z;
#pragma unroll
    for (int j = 0; j < 8; ++j) z[j] = (_Float16)0.f;
    return z;
}
__device__ __forceinline__ hf2 pkcvt(float a, float b) {
    return __builtin_bit_cast(hf2, __builtin_amdgcn_cvt_pkrtz(a, b));
}
__device__ __forceinline__ hf2 pkrelu(hf2 v) {
    hf2 z; z[0] = (_Float16)0.f; z[1] = (_Float16)0.f;
    return __builtin_elementwise_max(v, z);
}
__device__ __forceinline__ float waveSum(float v) {
#pragma unroll
    for (int s = 32; s; s >>= 1) v += __shfl_down(v, s, 64);
    return v;
}
#define ROWFN(r, lane) (((r) & 3) + 8*((r) >> 2) + 4*((lane) >> 5))

// ---------------- Kernel 0: transpose kx/q to [n][4] ----------------
__global__ __launch_bounds__(256) void prep0_kernel(
    const float* __restrict__ q, const float* __restrict__ kx,
    float* __restrict__ ws)
{
    float4* kxt = (float4*)(ws + KXT_OFF);
    float4* qt  = (float4*)(ws + QT_OFF);
    for (int e = blockIdx.x*256 + threadIdx.x; e < 2*Nn; e += gridDim.x*256) {
        const int b = e / Nn, n = e % Nn;
        float4 v;
        v.x = kx[(b*3+0)*Nn + n]; v.y = kx[(b*3+1)*Nn + n];
        v.z = kx[(b*3+2)*Nn + n]; v.w = 0.f;
        kxt[e] = v;
    }
    for (int e = blockIdx.x*256 + threadIdx.x; e < 2*Mn; e += gridDim.x*256) {
        const int b = e / Mn, m = e % Mn;
        float4 v;
        v.x = q[(b*3+0)*Mn + m]; v.y = q[(b*3+1)*Mn + m];
        v.z = q[(b*3+2)*Mn + m]; v.w = 0.f;
        qt[e] = v;
    }
}

// ---------------- Kernel A: gather once -> x-cache (f16) + packed mask + moments ----------------
__global__ __launch_bounds__(256) void gatherx_kernel(
    const int* __restrict__ idx, const int* __restrict__ mask,
    float* __restrict__ ws)
{
    __shared__ float red[4][16];
    const int b = blockIdx.y;
    const float4* kxt = (const float4*)(ws + KXT_OFF) + (size_t)b*Nn;
    const float4* qt  = (const float4*)(ws + QT_OFF)  + (size_t)b*Mn;
    _Float16* xf = (_Float16*)(ws + XF_OFF);
    unsigned short* m16 = (unsigned short*)(ws + MSK_OFF) + (size_t)b*25024;
    float v[14];
#pragma unroll
    for (int j = 0; j < 14; ++j) v[j] = 0.f;

    for (int i = blockIdx.x*256 + threadIdx.x; i < MK; i += G1*256) {
        const int mm = i >> 4;
        const int id = idx[(size_t)b*MK + i];
        const float4 kv = kxt[id];
        const float4 qv = qt[mm];
        const float ox = kv.x - qv.x, oy = kv.y - qv.y, oz = kv.z - qv.z;
        const float d  = sqrtf(ox*ox + oy*oy + oz*oz);
        const float inv = 1.0f / fmaxf(d, 1e-12f);
        const float x0 = ox*inv, x1 = oy*inv, x2 = oz*inv, x3 = d;

        const hf2 lo = pkcvt(x0, x1);
        const hf2 hi = pkcvt(x2, x3);
        hf4 pk;
        pk[0] = lo[0]; pk[1] = lo[1]; pk[2] = hi[0]; pk[3] = hi[1];
        *(hf4*)&xf[((size_t)b*MK + i)*4] = pk;

        const unsigned long long mb = __ballot(mask[(size_t)b*MK + i] != 0);
        if ((threadIdx.x & 63) == 0)
            *(unsigned long long*)&m16[i >> 4] = mb;

        v[0] += x0; v[1] += x1; v[2] += x2; v[3] += x3;
        v[4] += x0*x0; v[5] += x0*x1; v[6] += x0*x2; v[7] += x0*x3;
        v[8] += x1*x1; v[9] += x1*x2; v[10] += x1*x3;
        v[11] += x2*x2; v[12] += x2*x3; v[13] += x3*x3;
    }
    const int lane = threadIdx.x & 63, wv = threadIdx.x >> 6;
#pragma unroll
    for (int j = 0; j < 14; ++j) v[j] = waveSum(v[j]);
    if (lane == 0) {
#pragma unroll
        for (int j = 0; j < 14; ++j) red[wv][j] = v[j];
    }
    __syncthreads();
    if (threadIdx.x < 14)
        ws[SP_OFF + ((size_t)b*G1 + blockIdx.x)*16 + threadIdx.x] =
            red[0][threadIdx.x] + red[1][threadIdx.x] + red[2][threadIdx.x] + red[3][threadIdx.x];
}

// ---------------- Kernel B: block0: moments -> gn1 fold + beff + ab2 prescale;
//                  blocks 1..16: Weff + f16 weight conversion (data-independent) ----------------
__global__ void prep1_kernel(
    const float* __restrict__ ws_r,
    const float* __restrict__ w1, const float* __restrict__ b1,
    const float* __restrict__ g1, const float* __restrict__ be1,
    const float* __restrict__ w2, const float* __restrict__ pe_b2,
    const float* __restrict__ aw1, const float* __restrict__ ab1,
    const float* __restrict__ aw2, const float* __restrict__ ab2,
    float* __restrict__ ws)
{
    const int t = threadIdx.x;
    _Float16* WF = (_Float16*)(ws + WF16_OFF);

    if (blockIdx.x > 0) {
        // one element per thread: 16 blocks x 256 threads = 4096 elements
        const int e = (blockIdx.x - 1)*256 + t;
        const int o = e >> 6, c = e & 63;
        WF[e]        = (_Float16)w2[e];
        WF[4096 + e] = (_Float16)(aw2[e] * LOG2E);
        float acc = 0.f;
        for (int d = 0; d < 64; ++d) acc = fmaf(aw1[o*64 + d], w2[d*64 + c], acc);
        WF[8192 + e] = (_Float16)acc;
        return;
    }

    __shared__ double S[2][14];
    __shared__ float Eh[2][64], Eq[2][64];

    if (t < 28) {
        const int b = t / 14, j = t % 14;
        const float* p = ws_r + SP_OFF + (size_t)b*G1*16 + j;
        double acc = 0.0;
        for (int g = 0; g < G1; g += 4)
            acc += (double)p[(g+0)*16] + (double)p[(g+1)*16]
                 + (double)p[(g+2)*16] + (double)p[(g+3)*16];
        S[b][j] = acc;
    }
    __syncthreads();

    if (t < 128) {
        const int b = t >> 6, o = t & 63;
        const double inv = 1.0 / (double)MK;
        double mu[4];
#pragma unroll
        for (int c = 0; c < 4; ++c) mu[c] = S[b][c] * inv;
        double m2[4][4];
        {
            const int map[4][4] = {{0,1,2,3},{1,4,5,6},{2,5,7,8},{3,6,8,9}};
#pragma unroll
            for (int c = 0; c < 4; ++c)
#pragma unroll
                for (int c2 = 0; c2 < 4; ++c2)
                    m2[c][c2] = S[b][4 + map[c][c2]] * inv;
        }
        double w[4];
#pragma unroll
        for (int c = 0; c < 4; ++c) w[c] = (double)w1[o*4 + c];
        double s = 0.0, qd = 0.0;
#pragma unroll
        for (int c = 0; c < 4; ++c) {
            s += w[c] * mu[c];
#pragma unroll
            for (int c2 = 0; c2 < 4; ++c2) qd += w[c]*w[c2]*m2[c][c2];
        }
        const double bb = (double)b1[o];
        Eh[b][o] = (float)(s + bb);
        Eq[b][o] = (float)(qd + 2.0*bb*s + bb*bb);
    }
    __syncthreads();
    if (t < 128) {
        const int b = t >> 6, o = t & 63, g = o & ~7;
        float mg = 0.f, qg = 0.f;
#pragma unroll
        for (int j = 0; j < 8; ++j) { mg += Eh[b][g + j]; qg += Eq[b][g + j]; }
        mg *= 0.125f; qg *= 0.125f;
        const float var = fmaxf(qg - mg*mg, 0.f);
        const float a = g1[o] / sqrtf(var + GN_EPS);
        const float c1v = be1[o] - mg*a;
        _Float16* W1F = (_Float16*)(ws + W1F_OFF);
        hf8 wrow;
#pragma unroll
        for (int c = 0; c < 4; ++c) wrow[c] = (_Float16)(a * w1[o*4 + c]);
#pragma unroll
        for (int c = 4; c < 8; ++c) wrow[c] = (_Float16)0.f;
        *(hf8*)&W1F[(b*64 + o)*8] = wrow;
        ws[B1P_OFF + b*64 + o] = fmaf(a, b1[o], c1v);
    }
    if (t < 64) {
        float acc = ab1[t];
        for (int d = 0; d < 64; ++d) acc = fmaf(aw1[t*64 + d], pe_b2[d], acc);
        ws[BEFF_OFF + t] = acc;
    } else if (t < 128) {
        ws[AB2L_OFF + (t - 64)] = ab2[t - 64] * LOG2E;
    }
}

// ---------------- Kernel C: Σy, Σy² (y = Weff@r1), all-MFMA, interleaved cols ----------------
__global__ __launch_bounds__(256, 4) void pass2_kernel(
    const float* __restrict__ cws, float* __restrict__ ws)
{
    __shared__ __align__(16) _Float16 Xs[4][32][72];
    const int b = blockIdx.y;
    const int tid = threadIdx.x, lane = tid & 63, wv = tid >> 6;
    const int colA = lane & 31;
    const int klo = (lane >> 5) * 8;
    const _Float16* xf  = (const _Float16*)(cws + XF_OFF);
    const _Float16* WFe = (const _Float16*)(cws + WF16_OFF) + 8192;  // Weff
    const _Float16* W1F = (const _Float16*)(cws + W1F_OFF);

    hf8 BW[2][4];
#pragma unroll
    for (int jc = 0; jc < 2; ++jc)
#pragma unroll
        for (int ks = 0; ks < 4; ++ks)
            BW[jc][ks] = *(const hf8*)&WFe[(2*colA + jc)*64 + 16*ks + klo];
    hf8 BX[2];
    if (klo == 0) {
        BX[0] = *(const hf8*)&W1F[(b*64 + 2*colA)*8];
        BX[1] = *(const hf8*)&W1F[(b*64 + 2*colA + 1)*8];
    } else { BX[0] = zero8(); BX[1] = zero8(); }
    const float bias0 = cws[B1P_OFF + b*64 + 2*colA];
    const float bias1 = cws[B1P_OFF + b*64 + 2*colA + 1];

    float sh[2] = {0.f, 0.f}, sq[2] = {0.f, 0.f};

    for (int base = blockIdx.x * 128; base < MK; base += G2 * 128) {
        const int pt0 = base + 32*wv;
        hf8 ax = zero8();
        if (klo == 0) {
            hf4 xv = *(const hf4*)&xf[((size_t)b*MK + pt0 + colA)*4];
#pragma unroll
            for (int j = 0; j < 4; ++j) ax[j] = xv[j];
        }
        f32x16 r0 = splat16(bias0), r1t = splat16(bias1);
        r0  = mfma16(ax, BX[0], r0);
        r1t = mfma16(ax, BX[1], r1t);
#pragma unroll
        for (int r = 0; r < 16; ++r) {
            const int row = ROWFN(r, lane);
            *(hf2*)&Xs[wv][row][2*colA] = pkrelu(pkcvt(r0[r], r1t[r]));
        }
        hf8 A[4];
#pragma unroll
        for (int ks = 0; ks < 4; ++ks)
            A[ks] = *(const hf8*)&Xs[wv][colA][16*ks + klo];
#pragma unroll
        for (int jc = 0; jc < 2; ++jc) {
            f32x16 C = splat16(0.f);
#pragma unroll
            for (int ks = 0; ks < 4; ++ks) C = mfma16(A[ks], BW[jc][ks], C);
#pragma unroll
            for (int r = 0; r < 16; ++r) {
                const float vy = C[r];
                sh[jc] += vy;
                sq[jc] = fmaf(vy, vy, sq[jc]);
            }
        }
    }

#pragma unroll
    for (int jc = 0; jc < 2; ++jc) {
        sh[jc] += __shfl_xor(sh[jc], 32, 64);
        sq[jc] += __shfl_xor(sq[jc], 32, 64);
    }
    __syncthreads();
    float* red = (float*)Xs;   // [4][128]
    if (lane < 32) {
#pragma unroll
        for (int jc = 0; jc < 2; ++jc) {
            red[wv*128 +      2*colA + jc] = sh[jc];
            red[wv*128 + 64 + 2*colA + jc] = sq[jc];
        }
    }
    __syncthreads();
    if (tid < 128) {
        const float v = red[tid] + red[128 + tid] + red[256 + tid] + red[384 + tid];
        ws[YP_OFF + ((size_t)b*G2 + blockIdx.x)*128 + tid] = v;
    }
}

// ---------------- Kernel D1: parallel reduce of pass2 partials (one block per output) ----------------
__global__ __launch_bounds__(64) void prep2a_kernel(
    const float* __restrict__ ws_r, float* __restrict__ ws)
{
    const int o2 = blockIdx.x;            // [0,256): b = o2>>7, i = o2&127
    const int b = o2 >> 7, i = o2 & 127;
    const float* p = ws_r + YP_OFF + (size_t)b*G2*128 + i;
    double acc = 0.0;
    for (int g = threadIdx.x; g < G2; g += 64) acc += (double)p[(size_t)g*128];
#pragma unroll
    for (int s = 32; s; s >>= 1) acc += __shfl_down(acc, s, 64);
    if (threadIdx.x == 0) ((double*)(ws + YS_OFF))[o2] = acc;
}

// ---------------- Kernel D2: gn2 coeffs + fold into aw1/ab1 ----------------
__global__ void prep2b_kernel(const float* __restrict__ ws_r,
                              const float* __restrict__ g2, const float* __restrict__ be2,
                              const float* __restrict__ aw1, const float* __restrict__ ab1,
                              float* __restrict__ ws)
{
    __shared__ float EH[2][64], EQ[2][64];
    __shared__ float A2s[2][64];
    const int t = threadIdx.x;   // 256
    const double* YS = (const double*)(ws_r + YS_OFF);
    if (t < 128) {
        const int b = t >> 6, o = t & 63;
        const double invMK = 1.0 / (double)MK;
        const double my = YS[b*128 + o] * invMK;
        const double qy = YS[b*128 + 64 + o] * invMK;
        const double beff = (double)ws_r[BEFF_OFF + o];
        EH[b][o] = (float)(my + beff);
        EQ[b][o] = (float)(qy + 2.0*beff*my + beff*beff);
    }
    __syncthreads();
    if (t < 128) {
        const int b = t >> 6, o = t & 63, g = o & ~7;
        float mg = 0.f, qg = 0.f;
#pragma unroll
        for (int j = 0; j < 8; ++j) { mg += EH[b][g + j]; qg += EQ[b][g + j]; }
        mg *= 0.125f; qg *= 0.125f;
        const float var = fmaxf(qg - mg*mg, 0.f);
        const float a = g2[o] / sqrtf(var + GN_EPS);
        A2s[b][o] = a;
        ws[AB1P_OFF + b*64 + o] = fmaf(a, ab1[o], be2[o] - mg*a);
    }
    __syncthreads();
    _Float16* AW1P = (_Float16*)(ws + AW1P_OFF);
    for (int e = t; e < 8192; e += 256) {
        const int b = e >> 12, oc = e & 4095, o = oc >> 6;
        AW1P[e] = (_Float16)(A2s[b][o] * aw1[oc]);
    }
}

// ---------------- Kernel E: two-tile all-MFMA forward (64 pts/wave, B-fragments reused) ----------------
// Proven structure (stride-72 LDS, 4 MFMA chains/wave) + in-register mask.
// This round: softmax max-subtraction dropped (logits bounded; masked = exp2(-60000) = 0;
// all-masked case has its own branch) and GEMM3 bias dropped (constant over K ->
// cancels in softmax). Removes the serial fmax+shfl chain before the exps.
__global__ __launch_bounds__(256, 4) void pass3_kernel(
    const float* __restrict__ b2,
    const float* __restrict__ cws, float* __restrict__ out)
{
    __shared__ __align__(16) _Float16 Xs[8][32][72];   // [2*wv+t][row][col] 36.9 KB
    float* O = (float*)Xs;                             // aliased after barrier: [64][17]

    const int b = blockIdx.y;
    const int base = blockIdx.x * 256;                 // grid.x = 1563; last block partial
    const int tid = threadIdx.x;
    const int lane = tid & 63, wv = tid >> 6;
    const int colA = lane & 31;
    const int hi = lane >> 5;
    const int klo = hi * 8;

    const _Float16* xf   = (const _Float16*)(cws + XF_OFF);
    const _Float16* WF   = (const _Float16*)(cws + WF16_OFF);
    const _Float16* AW1P = (const _Float16*)(cws + AW1P_OFF) + (size_t)b*4096;
    const _Float16* W1F  = (const _Float16*)(cws + W1F_OFF);
    const unsigned short* m16 = (const unsigned short*)(cws + MSK_OFF) + (size_t)b*25024;

    int pt0[2];
    pt0[0] = base + 64*wv;
    pt0[1] = base + 64*wv + 32;
    unsigned mb[2];
#pragma unroll
    for (int t = 0; t < 2; ++t)
        mb[t] = (pt0[t] < MK) ? *(const unsigned*)(m16 + (pt0[t] >> 4)) : 0u;
    const unsigned mbs0 = __builtin_amdgcn_readfirstlane(mb[0]);
    const unsigned mbs1 = __builtin_amdgcn_readfirstlane(mb[1]);

    // ---- r1 via MFMA from cached x (both tiles; BX shared) ----
    {
        hf8 BX0, BX1;
        if (klo == 0) {
            BX0 = *(const hf8*)&W1F[(b*64 + 2*colA)*8];
            BX1 = *(const hf8*)&W1F[(b*64 + 2*colA + 1)*8];
        } else { BX0 = zero8(); BX1 = zero8(); }
        const float bias0 = cws[B1P_OFF + b*64 + 2*colA];
        const float bias1 = cws[B1P_OFF + b*64 + 2*colA + 1];
#pragma unroll
        for (int t = 0; t < 2; ++t) {
            hf8 ax = zero8();
            if (klo == 0 && pt0[t] < MK) {
                hf4 xv = *(const hf4*)&xf[((size_t)b*MK + pt0[t] + colA)*4];
#pragma unroll
                for (int j = 0; j < 4; ++j) ax[j] = xv[j];
            }
            f32x16 r0 = splat16(bias0), r1t = splat16(bias1);
            r0  = mfma16(ax, BX0, r0);
            r1t = mfma16(ax, BX1, r1t);
#pragma unroll
            for (int r = 0; r < 16; ++r) {
                const int row = ROWFN(r, lane);
                *(hf2*)&Xs[2*wv + t][row][2*colA] = pkrelu(pkcvt(r0[r], r1t[r]));
            }
        }
    }

    // ---- GEMM1: pe = r1 @ w2^T + b2 (B reused across tiles) ----
    hf2 pe_pk[2][16];   // packed pe kept for softmax (32 VGPRs)
    {
        f32x16 p00 = splat16(b2[2*colA]);
        f32x16 p01 = splat16(b2[2*colA + 1]);
        f32x16 p10 = p00, p11 = p01;
#pragma unroll
        for (int ks = 0; ks < 4; ++ks) {
            const int off = 16*ks + klo;
            hf8 a0  = *(const hf8*)&Xs[2*wv    ][colA][off];
            hf8 a1  = *(const hf8*)&Xs[2*wv + 1][colA][off];
            hf8 b0f = *(const hf8*)&WF[(2*colA)*64 + off];
            hf8 b1f = *(const hf8*)&WF[(2*colA + 1)*64 + off];
            p00 = mfma16(a0, b0f, p00);
            p01 = mfma16(a0, b1f, p01);
            p10 = mfma16(a1, b0f, p10);
            p11 = mfma16(a1, b1f, p11);
        }
#pragma unroll
        for (int r = 0; r < 16; ++r) {
            const int row = ROWFN(r, lane);
            pe_pk[0][r] = pkcvt(p00[r], p01[r]);
            pe_pk[1][r] = pkcvt(p10[r], p11[r]);
            *(hf2*)&Xs[2*wv    ][row][2*colA] = pe_pk[0][r];
            *(hf2*)&Xs[2*wv + 1][row][2*colA] = pe_pk[1][r];
        }
    }

    // ---- GEMM2: r2 = relu(pe @ (a2*aw1)^T + ab1') ----
    {
        f32x16 h00 = splat16(cws[AB1P_OFF + b*64 + 2*colA]);
        f32x16 h01 = splat16(cws[AB1P_OFF + b*64 + 2*colA + 1]);
        f32x16 h10 = h00, h11 = h01;
#pragma unroll
        for (int ks = 0; ks < 4; ++ks) {
            const int off = 16*ks + klo;
            hf8 a0  = *(const hf8*)&Xs[2*wv    ][colA][off];
            hf8 a1  = *(const hf8*)&Xs[2*wv + 1][colA][off];
            hf8 b0f = *(const hf8*)&AW1P[(2*colA)*64 + off];
            hf8 b1f = *(const hf8*)&AW1P[(2*colA + 1)*64 + off];
            h00 = mfma16(a0, b0f, h00);
            h01 = mfma16(a0, b1f, h01);
            h10 = mfma16(a1, b0f, h10);
            h11 = mfma16(a1, b1f, h11);
        }
#pragma unroll
        for (int r = 0; r < 16; ++r) {
            const int row = ROWFN(r, lane);
            *(hf2*)&Xs[2*wv    ][row][2*colA] = pkrelu(pkcvt(h00[r], h01[r]));
            *(hf2*)&Xs[2*wv + 1][row][2*colA] = pkrelu(pkcvt(h10[r], h11[r]));
        }
    }

    // ---- GEMM3: logits(log2) = r2 @ (aw2*log2e)^T  (bias cancels in softmax) ----
    f32x16 l00 = splat16(0.f);
    f32x16 l01 = splat16(0.f);
    f32x16 l10 = splat16(0.f), l11 = splat16(0.f);
#pragma unroll
    for (int ks = 0; ks < 4; ++ks) {
        const int off = 16*ks + klo;
        hf8 a0  = *(const hf8*)&Xs[2*wv    ][colA][off];
        hf8 a1  = *(const hf8*)&Xs[2*wv + 1][colA][off];
        hf8 b0f = *(const hf8*)&WF[4096 + (2*colA)*64 + off];
        hf8 b1f = *(const hf8*)&WF[4096 + (2*colA + 1)*64 + off];
        l00 = mfma16(a0, b0f, l00);
        l01 = mfma16(a0, b1f, l01);
        l10 = mfma16(a1, b0f, l10);
        l11 = mfma16(a1, b1f, l11);
    }

    // ---- mask applied in registers (bit = point row of C fragment; wave-uniform words) ----
    {
        const unsigned msh0 = mbs0 >> (4*hi);
        const unsigned msh1 = mbs1 >> (4*hi);
#pragma unroll
        for (int r = 0; r < 16; ++r) {
            const int bit = (r & 3) + 8*(r >> 2);   // compile-time constant
            const bool k0 = (msh0 >> bit) & 1u;
            const bool k1 = (msh1 >> bit) & 1u;
            l00[r] = k0 ? l00[r] : MASK_NEG;
            l01[r] = k0 ? l01[r] : MASK_NEG;
            l10[r] = k1 ? l10[r] : MASK_NEG;
            l11[r] = k1 ? l11[r] : MASK_NEG;
        }
    }

    __syncthreads();   // all Xs reads done; O may alias Xs

    // ---- softmax over K=16 (exp2 domain, no max subtraction) + weighted pe sum ----
    {
        auto softmax_tile = [&](const f32x16& lg, const hf2* pp, unsigned mbst,
                                int t, int j) {
#pragma unroll
            for (int mh = 0; mh < 2; ++mh) {
                float se, sw = 0.f;
                if (((mbst >> (16*mh)) & 0xFFFFu) != 0u) {
                    se = 0.f;
#pragma unroll
                    for (int rr = 0; rr < 8; ++rr) {
                        const float e = exp2f(lg[8*mh + rr]);   // masked -> exp2(-60000) = 0
                        se += e;
                        sw = fmaf(e, (float)pp[8*mh + rr][j], sw);
                    }
                } else {
                    se = 8.f;
#pragma unroll
                    for (int rr = 0; rr < 8; ++rr) sw += (float)pp[8*mh + rr][j];
                }
                se += __shfl_xor(se, 32, 64);
                sw += __shfl_xor(sw, 32, 64);
                if (lane < 32)
                    O[(2*lane + j)*17 + (4*wv + 2*t + mh)] = sw * __builtin_amdgcn_rcpf(se);
            }
        };
        softmax_tile(l00, pe_pk[0], mbs0, 0, 0);
        softmax_tile(l01, pe_pk[0], mbs0, 0, 1);
        softmax_tile(l10, pe_pk[1], mbs1, 1, 0);
        softmax_tile(l11, pe_pk[1], mbs1, 1, 1);
    }
    __syncthreads();

    {   // 64 ch x 16 m per block, one float4 per thread
        const int o = tid >> 2, mq = (tid & 3) * 4;
        const int m0 = blockIdx.x * 16;
        if (m0 + mq < Mn) {
            float4 v;
            v.x = O[o*17 + mq];     v.y = O[o*17 + mq + 1];
            v.z = O[o*17 + mq + 2]; v.w = O[o*17 + mq + 3];
            *(float4*)&out[((size_t)b*64 + o)*Mn + m0 + mq] = v;
        }
    }
}

extern "C" void kernel_launch(void* const* d_in, const int* in_sizes, int n_in,
                              void* d_out, int out_size, void* d_ws, size_t ws_size,
                              hipStream_t stream) {
    (void)in_sizes; (void)n_in; (void)out_size; (void)ws_size;
    const float* q    = (const float*)d_in[0];
    const float* kx   = (const float*)d_in[1];
    const int*   idx  = (const int*)  d_in[2];
    const int*   mask = (const int*)  d_in[3];
    const float* w1   = (const float*)d_in[4];
    const float* b1   = (const float*)d_in[5];
    const float* g1   = (const float*)d_in[6];
    const float* be1  = (const float*)d_in[7];
    const float* w2   = (const float*)d_in[8];
    const float* b2   = (const float*)d_in[9];
    const float* aw1  = (const float*)d_in[10];
    const float* ab1  = (const float*)d_in[11];
    const float* g2   = (const float*)d_in[12];
    const float* be2  = (const float*)d_in[13];
    const float* aw2  = (const float*)d_in[14];
    const float* ab2  = (const float*)d_in[15];
    float* out = (float*)d_out;
    float* ws  = (float*)d_ws;

    prep0_kernel<<<256, 256, 0, stream>>>(q, kx, ws);
    gatherx_kernel<<<dim3(G1, Bn), 256, 0, stream>>>(idx, mask, ws);
    prep1_kernel<<<17, 256, 0, stream>>>(ws, w1, b1, g1, be1, w2, b2, aw1, ab1, aw2, ab2, ws);
    pass2_kernel<<<dim3(G2, Bn), 256, 0, stream>>>(ws, ws);
    prep2a_kernel<<<256, 64, 0, stream>>>(ws, ws);
    prep2b_kernel<<<1, 256, 0, stream>>>(ws, g2, be2, aw1, ab1, ws);
    pass3_kernel<<<dim3((MK + 255)/256, Bn), 256, 0, stream>>>(b2, ws, out);
}